// Round 1
// baseline (3447.300 us; speedup 1.0000x reference)
//
#include <hip/hip_runtime.h>

#define EPS 1e-5f

// ---------------- InstanceNorm (optionally + residual), in-place safe ----------
// grid.x = B*C (one block per channel instance)
__global__ void inorm_k(const float* __restrict__ in, float* __restrict__ out,
                        int HW, int addres)
{
    __shared__ float sh[1024], sh2[1024];
    size_t base = (size_t)blockIdx.x * HW;
    const float* p = in + base;
    float* q = out + base;
    float s = 0.f, s2 = 0.f;
    for (int i = threadIdx.x; i < HW; i += blockDim.x) {
        float v = p[i]; s += v; s2 += v * v;
    }
    sh[threadIdx.x] = s; sh2[threadIdx.x] = s2;
    __syncthreads();
    for (int o = blockDim.x >> 1; o > 0; o >>= 1) {
        if ((int)threadIdx.x < o) {
            sh[threadIdx.x]  += sh[threadIdx.x + o];
            sh2[threadIdx.x] += sh2[threadIdx.x + o];
        }
        __syncthreads();
    }
    float mean = sh[0] / (float)HW;
    float var  = sh2[0] / (float)HW - mean * mean;
    float inv  = rsqrtf(var + EPS);
    for (int i = threadIdx.x; i < HW; i += blockDim.x) {
        float v = p[i];
        float r = (v - mean) * inv;
        q[i] = addres ? (r + v) : r;
    }
}

// ---------------- Direct 3x3 conv, pad=1, stride=1, NCHW / OIHW ----------------
// grid: (ceil(HW/256), Co, B); one output channel per block; weights in LDS.
__global__ void conv3x3_k(const float* __restrict__ in, const float* __restrict__ w,
                          const float* __restrict__ bias, float* __restrict__ out,
                          int Ci, int H, int W, int Co)
{
    extern __shared__ float sw[];          // Ci*9
    int co = blockIdx.y, b = blockIdx.z;
    int nw = Ci * 9;
    for (int i = threadIdx.x; i < nw; i += blockDim.x)
        sw[i] = w[(size_t)co * nw + i];
    __syncthreads();

    int HW = H * W;
    int p = blockIdx.x * blockDim.x + threadIdx.x;
    if (p >= HW) return;
    int y = p / W, x = p - y * W;
    const float* ib = in + (size_t)b * Ci * HW;
    float acc = bias[co];

    if (y > 0 && y < H - 1 && x > 0 && x < W - 1) {
        const float* r1 = ib + p;          // center of channel 0
        for (int ci = 0; ci < Ci; ci++, r1 += HW) {
            const float* wc = sw + ci * 9;
            const float* r0 = r1 - W;
            const float* r2 = r1 + W;
            acc += r0[-1]*wc[0] + r0[0]*wc[1] + r0[1]*wc[2];
            acc += r1[-1]*wc[3] + r1[0]*wc[4] + r1[1]*wc[5];
            acc += r2[-1]*wc[6] + r2[0]*wc[7] + r2[1]*wc[8];
        }
    } else {
        for (int ci = 0; ci < Ci; ci++) {
            const float* ic = ib + (size_t)ci * HW;
            const float* wc = sw + ci * 9;
            #pragma unroll
            for (int ky = 0; ky < 3; ky++) {
                int yy = y + ky - 1;
                if (yy < 0 || yy >= H) continue;
                const float* row = ic + yy * W;
                #pragma unroll
                for (int kx = 0; kx < 3; kx++) {
                    int xx = x + kx - 1;
                    if (xx < 0 || xx >= W) continue;
                    acc += row[xx] * wc[ky * 3 + kx];
                }
            }
        }
    }
    out[((size_t)b * Co + co) * HW + p] = acc;
}

// ---------------- 1x1 conv + residual (Ci == Co) -------------------------------
__global__ void conv1x1res_k(const float* __restrict__ in, const float* __restrict__ w,
                             const float* __restrict__ bias, float* __restrict__ out,
                             int C, int HW)
{
    extern __shared__ float sw[];          // C
    int co = blockIdx.y, b = blockIdx.z;
    for (int i = threadIdx.x; i < C; i += blockDim.x)
        sw[i] = w[(size_t)co * C + i];
    __syncthreads();
    int p = blockIdx.x * blockDim.x + threadIdx.x;
    if (p >= HW) return;
    const float* ib = in + (size_t)b * C * HW;
    float acc = bias[co];
    for (int ci = 0; ci < C; ci++)
        acc += ib[(size_t)ci * HW + p] * sw[ci];
    out[((size_t)b * C + co) * HW + p] = acc + ib[(size_t)co * HW + p];
}

// ---------------- PAC gaussian kernel: K[b,9,h,w] ------------------------------
// K = exp(-0.5 * sum_c (g[c, h+i-1, w+j-1] (0 if OOB) - g[c,h,w])^2)
__global__ void pack_k(const float* __restrict__ g, float* __restrict__ K,
                       int Cg, int H, int W)
{
    int b = blockIdx.y;
    int HW = H * W;
    int p = blockIdx.x * blockDim.x + threadIdx.x;
    if (p >= HW) return;
    int y = p / W, x = p - y * W;
    float acc[9];
    #pragma unroll
    for (int t = 0; t < 9; t++) acc[t] = 0.f;
    const float* gb = g + (size_t)b * Cg * HW;
    for (int c = 0; c < Cg; c++) {
        const float* gc = gb + (size_t)c * HW;
        float ctr = gc[p];
        #pragma unroll
        for (int i = 0; i < 3; i++) {
            int yy = y + i - 1;
            bool yok = (yy >= 0 && yy < H);
            #pragma unroll
            for (int j = 0; j < 3; j++) {
                int xx = x + j - 1;
                float nbr = (yok && xx >= 0 && xx < W) ? gc[yy * W + xx] : 0.f;
                float d = nbr - ctr;
                acc[i * 3 + j] += d * d;
            }
        }
    }
    #pragma unroll
    for (int t = 0; t < 9; t++)
        K[((size_t)(b * 9 + t)) * HW + p] = expf(-0.5f * acc[t]);
}

// ---------------- PacConvTranspose2d (k=3, s=2, p=1, out_pad=1) ----------------
// out[b,co,h,w] = bias[co] + sum_{i,j valid} K[b,ij,h,w] *
//                 sum_ci x[b,ci,(h+i-1)/2,(w+j-1)/2] * w[ci,co,ij]
// valid: u=h+i-1 even AND 0<=u<=2*Hi-2  (u=2*Hi is even but OOB!)
__global__ void pacct_k(const float* __restrict__ x, const float* __restrict__ K,
                        const float* __restrict__ w, const float* __restrict__ bias,
                        float* __restrict__ out, int Cin, int Cout, int Hi, int Wi)
{
    extern __shared__ float sw[];          // Cin*9, layout [ci][tap]
    int H = 2 * Hi, W = 2 * Wi;
    int HW = H * W, HWi = Hi * Wi;
    int co = blockIdx.y, b = blockIdx.z;
    for (int i = threadIdx.x; i < Cin * 9; i += blockDim.x) {
        int ci = i / 9, t = i - ci * 9;
        sw[i] = w[((size_t)ci * Cout + co) * 9 + t];   // wf[co,ci,t] = w[ci,co,t]
    }
    __syncthreads();
    int p = blockIdx.x * blockDim.x + threadIdx.x;
    if (p >= HW) return;
    int y = p / W, xc = p - y * W;
    float acc = bias[co];
    const float* xb = x + (size_t)b * Cin * HWi;
    const float* Kb = K + (size_t)b * 9 * HW;
    #pragma unroll
    for (int i = 0; i < 3; i++) {
        int u = y + i - 1;
        if (u < 0 || u > 2 * Hi - 2 || (u & 1)) continue;
        int ui = u >> 1;
        #pragma unroll
        for (int j = 0; j < 3; j++) {
            int v = xc + j - 1;
            if (v < 0 || v > 2 * Wi - 2 || (v & 1)) continue;
            int vi = v >> 1;
            float kk = Kb[(size_t)(i * 3 + j) * HW + p];
            const float* xp = xb + (size_t)ui * Wi + vi;
            float dot = 0.f;
            for (int ci = 0; ci < Cin; ci++)
                dot += xp[(size_t)ci * HWi] * sw[ci * 9 + (i * 3 + j)];
            acc += kk * dot;
        }
    }
    out[((size_t)b * Cout + co) * HW + p] = acc;
}

// ------------------------------------------------------------------------------
extern "C" void kernel_launch(void* const* d_in, const int* in_sizes, int n_in,
                              void* d_out, int out_size, void* d_ws, size_t ws_size,
                              hipStream_t stream)
{
    const float* x   = (const float*)d_in[0];   // (2,256,64,64)
    const float* ef2 = (const float*)d_in[1];   // (2,64,128,128)
    const float* ef1 = (const float*)d_in[2];   // (2,32,256,256)
    const float* Wd  = (const float*)d_in[3];   // (128,256,3,3)
    const float* bd  = (const float*)d_in[4];
    const float* Wm  = (const float*)d_in[5];   // (128,128,1,1)
    const float* bm  = (const float*)d_in[6];
    const float* Wa2 = (const float*)d_in[7];   // (128,64,3,3)
    const float* ba2 = (const float*)d_in[8];
    const float* Wa1 = (const float*)d_in[9];   // (64,32,3,3)
    const float* ba1 = (const float*)d_in[10];
    const float* W16 = (const float*)d_in[11];  // (128,64,3,3) convT (Cin,Cout,kh,kw)
    const float* b16 = (const float*)d_in[12];
    const float* W20 = (const float*)d_in[13];  // (64,32,3,3)
    const float* b20 = (const float*)d_in[14];
    const float* W24 = (const float*)d_in[15];  // (3,32,3,3)
    const float* b24 = (const float*)d_in[16];
    float* out = (float*)d_out;                 // (2,3,256,256)

    // workspace carve (floats); total 16,154,624 floats = 64.6 MB
    float* Wf = (float*)d_ws;
    float* K2 = Wf;                    // 2*9*128*128   =   294,912
    float* x3 = K2 + 294912;           // 2*64*128*128  = 2,097,152
    float* x5 = x3 + 2097152;          // 2*32*256*256  = 4,194,304
    float* K1 = x5 + 4194304;          // 2*9*256*256   = 1,179,648
    float* E  = K1 + 1179648;          // reuse region, 8,388,608 floats
    float* t0 = E;                     // 2*256*64*64   = 2,097,152
    float* x1 = E + 2097152;           // 2*128*64*64   = 1,048,576
    float* x2 = E + 3145728;           // 2*128*64*64   = 1,048,576
    float* g2 = E + 4194304;           // 2*128*128*128 = 4,194,304
    float* g1 = E;                     // 2*64*256*256  = 8,388,608 (aliases t0..g2, all dead)

    // 1) inorm(x) -> t0
    inorm_k<<<dim3(2 * 256), dim3(1024), 0, stream>>>(x, t0, 64 * 64, 0);
    // 2) conv_down 256->128 @64x64 -> x1
    conv3x3_k<<<dim3(16, 128, 2), dim3(256), 256 * 9 * sizeof(float), stream>>>(
        t0, Wd, bd, x1, 256, 64, 64, 128);
    // 3) 1x1 conv + residual -> x2
    conv1x1res_k<<<dim3(16, 128, 2), dim3(256), 128 * sizeof(float), stream>>>(
        x1, Wm, bm, x2, 128, 4096);
    // 4) adjust_ef_lv2: 64->128 @128x128 -> g2
    conv3x3_k<<<dim3(64, 128, 2), dim3(256), 64 * 9 * sizeof(float), stream>>>(
        ef2, Wa2, ba2, g2, 64, 128, 128, 128);
    // 5) PAC kernel from g2 -> K2
    pack_k<<<dim3(64, 2), dim3(256), 0, stream>>>(g2, K2, 128, 128, 128);
    // 6) PacConvT 128->64, 64^2 -> 128^2 -> x3
    pacct_k<<<dim3(64, 64, 2), dim3(256), 128 * 9 * sizeof(float), stream>>>(
        x2, K2, W16, b16, x3, 128, 64, 64, 64);
    // 7) inorm+res twice (in place)
    inorm_k<<<dim3(2 * 64), dim3(1024), 0, stream>>>(x3, x3, 128 * 128, 1);
    inorm_k<<<dim3(2 * 64), dim3(1024), 0, stream>>>(x3, x3, 128 * 128, 1);
    // 8) adjust_ef_lv1: 32->64 @256x256 -> g1
    conv3x3_k<<<dim3(256, 64, 2), dim3(256), 32 * 9 * sizeof(float), stream>>>(
        ef1, Wa1, ba1, g1, 32, 256, 256, 64);
    // 9) PAC kernel from g1 -> K1
    pack_k<<<dim3(256, 2), dim3(256), 0, stream>>>(g1, K1, 64, 256, 256);
    // 10) PacConvT 64->32, 128^2 -> 256^2 -> x5
    pacct_k<<<dim3(256, 32, 2), dim3(256), 64 * 9 * sizeof(float), stream>>>(
        x3, K1, W20, b20, x5, 64, 32, 128, 128);
    // 11) inorm+res twice (in place)
    inorm_k<<<dim3(2 * 32), dim3(1024), 0, stream>>>(x5, x5, 256 * 256, 1);
    inorm_k<<<dim3(2 * 32), dim3(1024), 0, stream>>>(x5, x5, 256 * 256, 1);
    // 12) final conv 32->3 @256x256 -> out
    conv3x3_k<<<dim3(256, 3, 2), dim3(256), 32 * 9 * sizeof(float), stream>>>(
        x5, W24, b24, out, 32, 256, 256, 3);
}

// Round 2
// 2135.295 us; speedup vs baseline: 1.6144x; 1.6144x over previous
//
#include <hip/hip_runtime.h>

#define EPS 1e-5f

// ---------------- InstanceNorm; mode 0: inorm(x); mode 2: x + 2*inorm(x) ------
__global__ __launch_bounds__(1024) void inorm_k(const float* __restrict__ in,
                                                float* __restrict__ out,
                                                int HW, int mode)
{
    __shared__ float sh[1024], sh2[1024];
    size_t base = (size_t)blockIdx.x * HW;
    const float* p = in + base;
    float* q = out + base;
    float s = 0.f, s2 = 0.f;
    for (int i = threadIdx.x; i < HW; i += blockDim.x) {
        float v = p[i]; s += v; s2 += v * v;
    }
    sh[threadIdx.x] = s; sh2[threadIdx.x] = s2;
    __syncthreads();
    for (int o = blockDim.x >> 1; o > 0; o >>= 1) {
        if ((int)threadIdx.x < o) {
            sh[threadIdx.x]  += sh[threadIdx.x + o];
            sh2[threadIdx.x] += sh2[threadIdx.x + o];
        }
        __syncthreads();
    }
    float mean = sh[0] / (float)HW;
    float var  = sh2[0] / (float)HW - mean * mean;
    float inv  = rsqrtf(var + EPS);
    for (int i = threadIdx.x; i < HW; i += blockDim.x) {
        float v = p[i];
        float r = (v - mean) * inv;
        q[i] = (mode == 0) ? r : v + 2.f * r;
    }
}

// ---------------- Tiled 3x3 conv, pad=1: 16x8 spatial tile, NCO co/block ------
// block 128 = 16x16/... (tx 0..15, ty 0..7); weights via uniform (scalar) loads
template<int NCO>
__global__ __launch_bounds__(128) void conv3x3_t(const float* __restrict__ in,
    const float* __restrict__ w, const float* __restrict__ bias,
    float* __restrict__ out, int Ci, int H, int W, int Co)
{
    const int ST = 24;                       // row stride: 24 mod 32 -> 2-way (free)
    __shared__ float tile[4][10 * ST];       // 4 ci x (8+2) rows x (16+2) cols
    int tid = threadIdx.x;
    int wtiles = W >> 4;
    int sp = blockIdx.x;
    int x0 = (sp % wtiles) << 4, y0 = (sp / wtiles) << 3;
    int co0 = blockIdx.y * NCO, b = blockIdx.z;
    int tx = tid & 15, ty = tid >> 4;

    int jcl[NCO];
    float acc[NCO];
    #pragma unroll
    for (int j = 0; j < NCO; j++) {
        jcl[j] = (co0 + j < Co) ? (co0 + j) : (Co - 1);
        acc[j] = bias[jcl[j]];
    }
    const float* ib = in + (size_t)b * Ci * H * W;

    for (int ci0 = 0; ci0 < Ci; ci0 += 4) {
        __syncthreads();
        for (int idx = tid; idx < 4 * 180; idx += 128) {
            int c = idx / 180, rem = idx - c * 180;
            int r = rem / 18, col = rem - r * 18;
            int gy = y0 + r - 1, gx = x0 + col - 1;
            float v = 0.f;
            if (gy >= 0 && gy < H && gx >= 0 && gx < W)
                v = ib[((size_t)(ci0 + c) * H + gy) * W + gx];
            tile[c][r * ST + col] = v;
        }
        __syncthreads();
        #pragma unroll
        for (int c = 0; c < 4; c++) {
            const float* tp = &tile[c][ty * ST + tx];
            float v0 = tp[0],        v1 = tp[1],        v2 = tp[2];
            float v3 = tp[ST],       v4 = tp[ST + 1],   v5 = tp[ST + 2];
            float v6 = tp[2 * ST],   v7 = tp[2 * ST + 1], v8 = tp[2 * ST + 2];
            #pragma unroll
            for (int j = 0; j < NCO; j++) {
                const float* wj = w + ((size_t)jcl[j] * Ci + (ci0 + c)) * 9;
                acc[j] += v0 * wj[0] + v1 * wj[1] + v2 * wj[2]
                        + v3 * wj[3] + v4 * wj[4] + v5 * wj[5]
                        + v6 * wj[6] + v7 * wj[7] + v8 * wj[8];
            }
        }
    }
    int y = y0 + ty, x = x0 + tx;
    #pragma unroll
    for (int j = 0; j < NCO; j++)
        if (co0 + j < Co)
            out[((size_t)(b * Co + co0 + j) * H + y) * W + x] = acc[j];
}

// ---------------- 1x1 conv + residual (Ci == Co), 16 co per block -------------
__global__ __launch_bounds__(256) void conv1x1res_k(const float* __restrict__ in,
    const float* __restrict__ w, const float* __restrict__ bias,
    float* __restrict__ out, int C, int HW)
{
    int co0 = blockIdx.y * 16, b = blockIdx.z;
    int p = blockIdx.x * 256 + threadIdx.x;
    const float* ib = in + (size_t)b * C * HW;
    float acc[16];
    #pragma unroll
    for (int j = 0; j < 16; j++) acc[j] = bias[co0 + j];
    for (int ci = 0; ci < C; ci++) {
        float xv = ib[(size_t)ci * HW + p];
        #pragma unroll
        for (int j = 0; j < 16; j++)
            acc[j] += xv * w[(size_t)(co0 + j) * C + ci];
    }
    #pragma unroll
    for (int j = 0; j < 16; j++)
        out[((size_t)(b * C + co0 + j)) * HW + p] = acc[j] + ib[(size_t)(co0 + j) * HW + p];
}

// ---------------- PAC gaussian kernel, LDS-tiled (16x8 tile) ------------------
__global__ __launch_bounds__(128) void pack_t(const float* __restrict__ g,
    float* __restrict__ K, int Cg, int H, int W)
{
    const int ST = 24;
    __shared__ float tile[4][10 * ST];
    int tid = threadIdx.x;
    int wtiles = W >> 4;
    int sp = blockIdx.x;
    int x0 = (sp % wtiles) << 4, y0 = (sp / wtiles) << 3;
    int b = blockIdx.y;
    int tx = tid & 15, ty = tid >> 4;
    float acc[9];
    #pragma unroll
    for (int t = 0; t < 9; t++) acc[t] = 0.f;
    const float* gb = g + (size_t)b * Cg * H * W;

    for (int ci0 = 0; ci0 < Cg; ci0 += 4) {
        __syncthreads();
        for (int idx = tid; idx < 4 * 180; idx += 128) {
            int c = idx / 180, rem = idx - c * 180;
            int r = rem / 18, col = rem - r * 18;
            int gy = y0 + r - 1, gx = x0 + col - 1;
            float v = 0.f;
            if (gy >= 0 && gy < H && gx >= 0 && gx < W)
                v = gb[((size_t)(ci0 + c) * H + gy) * W + gx];
            tile[c][r * ST + col] = v;
        }
        __syncthreads();
        #pragma unroll
        for (int c = 0; c < 4; c++) {
            const float* tp = &tile[c][ty * ST + tx];
            float v0 = tp[0],      v1 = tp[1],          v2 = tp[2];
            float v3 = tp[ST],     ctr = tp[ST + 1],    v5 = tp[ST + 2];
            float v6 = tp[2 * ST], v7 = tp[2 * ST + 1], v8 = tp[2 * ST + 2];
            float d;
            d = v0 - ctr; acc[0] += d * d;
            d = v1 - ctr; acc[1] += d * d;
            d = v2 - ctr; acc[2] += d * d;
            d = v3 - ctr; acc[3] += d * d;
            d = v5 - ctr; acc[5] += d * d;
            d = v6 - ctr; acc[6] += d * d;
            d = v7 - ctr; acc[7] += d * d;
            d = v8 - ctr; acc[8] += d * d;
        }
    }
    int HW = H * W;
    int p = (y0 + ty) * W + x0 + tx;
    #pragma unroll
    for (int t = 0; t < 9; t++)
        K[((size_t)(b * 9 + t)) * HW + p] = expf(-0.5f * acc[t]);
}

// ---------------- PacConvTranspose2d, wave-parity version ---------------------
// block 256 = 4 waves; wave w owns parity class (py,px)=(w>>1,w&1) of a 16x16
// output tile; tap set per parity is wave-uniform -> scalar weight loads.
template<int NCO>
__global__ __launch_bounds__(256) void pacct_t(const float* __restrict__ xin,
    const float* __restrict__ Kk, const float* __restrict__ w,
    const float* __restrict__ bias, float* __restrict__ out,
    int Cin, int Cout, int Hi, int Wi)
{
    const int ST = 12;
    __shared__ float tile[4][9 * ST];        // 4 ci x 9 rows x 9 cols (pad 12)
    int H = Hi << 1, W = Wi << 1;
    int HW = H * W, HWi = Hi * Wi;
    int tid = threadIdx.x;
    int wtiles = W >> 4;
    int sp = blockIdx.x;
    int x0 = (sp % wtiles) << 4, y0 = (sp / wtiles) << 4;
    int co0 = blockIdx.y * NCO, b = blockIdx.z;
    int wv = tid >> 6, l = tid & 63;
    int py = wv >> 1, px = wv & 1;
    int ly = l >> 3, lx = l & 7;
    int y = y0 + 2 * ly + py, x = x0 + 2 * lx + px;
    int ui0 = y0 >> 1, vi0 = x0 >> 1;

    int ns = (py + 1) * (px + 1);            // wave-uniform: 1,2,2,4
    float Kv[4]; int off[4]; int tus[4];
    const float* Kb = Kk + (size_t)b * 9 * HW;
    {
        int s = 0;
        for (int si = 0; si <= py; si++)
            for (int sj = 0; sj <= px; sj++) {
                int i = py ? 2 * si : 1;
                int j = px ? 2 * sj : 1;
                int t = 3 * i + j;
                int ui = (y + i - 1) >> 1, vi = (x + j - 1) >> 1;
                off[s] = (ui - ui0) * ST + (vi - vi0);
                Kv[s]  = Kb[(size_t)t * HW + y * W + x];
                tus[s] = __builtin_amdgcn_readfirstlane(t);
                s++;
            }
    }
    float acc[NCO];
    #pragma unroll
    for (int j = 0; j < NCO; j++) acc[j] = bias[co0 + j];
    const float* xb = xin + (size_t)b * Cin * HWi;

    for (int ci0 = 0; ci0 < Cin; ci0 += 4) {
        __syncthreads();
        for (int idx = tid; idx < 4 * 81; idx += 256) {
            int c = idx / 81, rem = idx - c * 81;
            int r = rem / 9, col = rem - r * 9;
            int ui = ui0 + r, vi = vi0 + col;
            float v = 0.f;
            if (ui < Hi && vi < Wi)
                v = xb[((size_t)(ci0 + c) * Hi + ui) * Wi + vi];
            tile[c][r * ST + col] = v;
        }
        __syncthreads();
        #pragma unroll
        for (int c = 0; c < 4; c++) {
            const float* wr = w + ((size_t)(ci0 + c) * Cout + co0) * 9;
            if (ns == 1) {
                float s0 = Kv[0] * tile[c][off[0]];
                int t0 = tus[0];
                #pragma unroll
                for (int j = 0; j < NCO; j++)
                    acc[j] += s0 * wr[j * 9 + t0];
            } else if (ns == 2) {
                float s0 = Kv[0] * tile[c][off[0]];
                float s1 = Kv[1] * tile[c][off[1]];
                int t0 = tus[0], t1 = tus[1];
                #pragma unroll
                for (int j = 0; j < NCO; j++)
                    acc[j] += s0 * wr[j * 9 + t0] + s1 * wr[j * 9 + t1];
            } else {
                float s0 = Kv[0] * tile[c][off[0]];
                float s1 = Kv[1] * tile[c][off[1]];
                float s2 = Kv[2] * tile[c][off[2]];
                float s3 = Kv[3] * tile[c][off[3]];
                int t0 = tus[0], t1 = tus[1], t2 = tus[2], t3 = tus[3];
                #pragma unroll
                for (int j = 0; j < NCO; j++)
                    acc[j] += s0 * wr[j * 9 + t0] + s1 * wr[j * 9 + t1]
                            + s2 * wr[j * 9 + t2] + s3 * wr[j * 9 + t3];
            }
        }
    }
    #pragma unroll
    for (int j = 0; j < NCO; j++)
        out[((size_t)(b * Cout + co0 + j)) * HW + y * W + x] = acc[j];
}

// ------------------------------------------------------------------------------
extern "C" void kernel_launch(void* const* d_in, const int* in_sizes, int n_in,
                              void* d_out, int out_size, void* d_ws, size_t ws_size,
                              hipStream_t stream)
{
    const float* x   = (const float*)d_in[0];   // (2,256,64,64)
    const float* ef2 = (const float*)d_in[1];   // (2,64,128,128)
    const float* ef1 = (const float*)d_in[2];   // (2,32,256,256)
    const float* Wd  = (const float*)d_in[3];
    const float* bd  = (const float*)d_in[4];
    const float* Wm  = (const float*)d_in[5];
    const float* bm  = (const float*)d_in[6];
    const float* Wa2 = (const float*)d_in[7];
    const float* ba2 = (const float*)d_in[8];
    const float* Wa1 = (const float*)d_in[9];
    const float* ba1 = (const float*)d_in[10];
    const float* W16 = (const float*)d_in[11];  // (128,64,3,3) convT layout
    const float* b16 = (const float*)d_in[12];
    const float* W20 = (const float*)d_in[13];  // (64,32,3,3)
    const float* b20 = (const float*)d_in[14];
    const float* W24 = (const float*)d_in[15];  // (3,32,3,3)
    const float* b24 = (const float*)d_in[16];
    float* out = (float*)d_out;                 // (2,3,256,256)

    float* Wf = (float*)d_ws;
    float* K2 = Wf;                    // 2*9*128*128   =   294,912
    float* x3 = K2 + 294912;           // 2*64*128*128  = 2,097,152
    float* x5 = x3 + 2097152;          // 2*32*256*256  = 4,194,304
    float* K1 = x5 + 4194304;          // 2*9*256*256   = 1,179,648
    float* E  = K1 + 1179648;          // reuse region
    float* t0 = E;                     // 2*256*64*64
    float* x1 = E + 2097152;           // 2*128*64*64
    float* x2 = E + 3145728;           // 2*128*64*64
    float* g2 = E + 4194304;           // 2*128*128*128
    float* g1 = E;                     // 2*64*256*256 (aliases t0..g2, all dead)

    // 1) inorm(x) -> t0
    inorm_k<<<dim3(512), dim3(1024), 0, stream>>>(x, t0, 4096, 0);
    // 2) conv_down 256->128 @64x64 -> x1 : sp=(64/16)*(64/8)=32, co=8, b=2
    conv3x3_t<16><<<dim3(32, 8, 2), dim3(128), 0, stream>>>(t0, Wd, bd, x1, 256, 64, 64, 128);
    // 3) 1x1 + residual -> x2
    conv1x1res_k<<<dim3(16, 8, 2), dim3(256), 0, stream>>>(x1, Wm, bm, x2, 128, 4096);
    // 4) adjust_ef_lv2 64->128 @128x128 -> g2 : sp=8*16=128
    conv3x3_t<16><<<dim3(128, 8, 2), dim3(128), 0, stream>>>(ef2, Wa2, ba2, g2, 64, 128, 128, 128);
    // 5) PAC kernel K2 : sp=128
    pack_t<<<dim3(128, 2), dim3(128), 0, stream>>>(g2, K2, 128, 128, 128);
    // 6) PacConvT 128->64, 64^2->128^2 -> x3 : sp=(128/16)^2=64, co=4
    pacct_t<16><<<dim3(64, 4, 2), dim3(256), 0, stream>>>(x2, K2, W16, b16, x3, 128, 64, 64, 64);
    // 7) double inorm+res fused: x3 = x3 + 2*inorm(x3)
    inorm_k<<<dim3(128), dim3(1024), 0, stream>>>(x3, x3, 16384, 2);
    // 8) adjust_ef_lv1 32->64 @256x256 -> g1 : sp=16*32=512
    conv3x3_t<16><<<dim3(512, 4, 2), dim3(128), 0, stream>>>(ef1, Wa1, ba1, g1, 32, 256, 256, 64);
    // 9) PAC kernel K1 : sp=512
    pack_t<<<dim3(512, 2), dim3(128), 0, stream>>>(g1, K1, 64, 256, 256);
    // 10) PacConvT 64->32, 128^2->256^2 -> x5 : sp=(256/16)^2=256, co=2
    pacct_t<16><<<dim3(256, 2, 2), dim3(256), 0, stream>>>(x3, K1, W20, b20, x5, 64, 32, 128, 128);
    // 11) double inorm+res fused
    inorm_k<<<dim3(64), dim3(1024), 0, stream>>>(x5, x5, 65536, 2);
    // 12) final conv 32->3 @256x256 -> out : sp=512, co=1
    conv3x3_t<4><<<dim3(512, 1, 2), dim3(128), 0, stream>>>(x5, W24, b24, out, 32, 256, 256, 3);
}

// Round 3
// 633.000 us; speedup vs baseline: 5.4460x; 3.3733x over previous
//
#include <hip/hip_runtime.h>

#define EPS 1e-5f

// ================= InstanceNorm: stats (atomic) + apply ========================
// each block reduces 2048 contiguous elements (2048 | HW for all uses)
__global__ __launch_bounds__(256) void istat_k(const float* __restrict__ in,
                                               float* st, int HW)
{
    __shared__ float sh[256], sh2[256];
    size_t base = (size_t)blockIdx.x * 2048 + threadIdx.x * 8;
    float4 a = *(const float4*)(in + base);
    float4 b = *(const float4*)(in + base + 4);
    float s  = a.x + a.y + a.z + a.w + b.x + b.y + b.z + b.w;
    float s2 = a.x*a.x + a.y*a.y + a.z*a.z + a.w*a.w
             + b.x*b.x + b.y*b.y + b.z*b.z + b.w*b.w;
    sh[threadIdx.x] = s; sh2[threadIdx.x] = s2;
    __syncthreads();
    for (int o = 128; o > 0; o >>= 1) {
        if ((int)threadIdx.x < o) {
            sh[threadIdx.x] += sh[threadIdx.x + o];
            sh2[threadIdx.x] += sh2[threadIdx.x + o];
        }
        __syncthreads();
    }
    if (threadIdx.x == 0) {
        int ch = (int)(((size_t)blockIdx.x * 2048) / (size_t)HW);
        atomicAdd(&st[2 * ch],     sh[0]);
        atomicAdd(&st[2 * ch + 1], sh2[0]);
    }
}

// mode 0: r ; mode 2: v + 2r   (in-place safe: no __restrict__)
__global__ __launch_bounds__(256) void iapply_k(const float* in, const float* st,
                                                float* out, int HW, int mode)
{
    int i4 = (blockIdx.x * 256 + threadIdx.x) * 4;
    int ch = i4 / HW;
    float s = st[2 * ch], s2 = st[2 * ch + 1];
    float m = s / (float)HW;
    float var = s2 / (float)HW - m * m;
    float inv = rsqrtf(var + EPS);
    float4 v = *(const float4*)(in + i4);
    float4 r;
    r.x = (v.x - m) * inv; r.y = (v.y - m) * inv;
    r.z = (v.z - m) * inv; r.w = (v.w - m) * inv;
    if (mode == 2) {
        r.x = v.x + 2.f * r.x; r.y = v.y + 2.f * r.y;
        r.z = v.z + 2.f * r.z; r.w = v.w + 2.f * r.w;
    }
    *(float4*)(out + i4) = r;
}

// ================= Direct 3x3 conv (pad=1): 4 px/thread, shfl halo =============
// grid.x*256 == H*(W/4) exactly; grid.y = Co/NCO; grid.z = B*NS
template<int NCO>
__global__ __launch_bounds__(256) void conv3x3_d(const float* __restrict__ in,
    const float* __restrict__ w, const float* __restrict__ bias,
    float* __restrict__ outp, int Ci, int CS, int H, int W, int Co, int NS,
    size_t SS)
{
    int z = blockIdx.z;
    int b = z / NS, sl = z - b * NS;
    int WC = W >> 2;
    int idx = blockIdx.x * 256 + threadIdx.x;
    int xc = idx % WC, y = idx / WC;
    int x0 = xc << 2;
    bool lz = (x0 == 0), rz = (x0 + 4 == W);
    int co0 = blockIdx.y * NCO;
    float acc[NCO][4];
    #pragma unroll
    for (int j = 0; j < NCO; j++)
        #pragma unroll
        for (int p = 0; p < 4; p++) acc[j][p] = 0.f;

    const float* ib = in + ((size_t)b * Ci + sl * CS) * H * W;
    for (int ci = 0; ci < CS; ci++) {
        const float* ic = ib + (size_t)ci * H * W;
        float e[3][6];
        #pragma unroll
        for (int r = 0; r < 3; r++) {
            int yy = y + r - 1;
            float4 v = make_float4(0.f, 0.f, 0.f, 0.f);
            if (yy >= 0 && yy < H)
                v = *(const float4*)(ic + (size_t)yy * W + x0);
            float lf = __shfl_up(v.w, 1);
            float rt = __shfl_down(v.x, 1);
            e[r][0] = lz ? 0.f : lf;
            e[r][1] = v.x; e[r][2] = v.y; e[r][3] = v.z; e[r][4] = v.w;
            e[r][5] = rz ? 0.f : rt;
        }
        int cig = sl * CS + ci;
        #pragma unroll
        for (int j = 0; j < NCO; j++) {
            const float* wj = w + ((size_t)(co0 + j) * Ci + cig) * 9;
            #pragma unroll
            for (int r = 0; r < 3; r++) {
                float w0 = wj[3 * r], w1 = wj[3 * r + 1], w2 = wj[3 * r + 2];
                #pragma unroll
                for (int p = 0; p < 4; p++)
                    acc[j][p] = fmaf(e[r][p], w0,
                                fmaf(e[r][p + 1], w1,
                                fmaf(e[r][p + 2], w2, acc[j][p])));
            }
        }
    }
    size_t HW = (size_t)H * W;
    #pragma unroll
    for (int j = 0; j < NCO; j++) {
        float bb = bias ? bias[co0 + j] : 0.f;
        float4 o = make_float4(acc[j][0] + bb, acc[j][1] + bb,
                               acc[j][2] + bb, acc[j][3] + bb);
        float* op = outp + (size_t)sl * SS
                  + ((size_t)b * Co + co0 + j) * HW + (size_t)y * W + x0;
        *(float4*)op = o;
    }
}

// ================= Direct 1x1 conv: 4 px/thread, partial out ===================
template<int NCO>
__global__ __launch_bounds__(256) void conv1x1_d(const float* __restrict__ in,
    const float* __restrict__ w, float* __restrict__ outp,
    int C, int CS, int HW, int NS, size_t SS)
{
    int z = blockIdx.z;
    int b = z / NS, sl = z - b * NS;
    int x0 = (blockIdx.x * 256 + threadIdx.x) * 4;
    int co0 = blockIdx.y * NCO;
    float acc[NCO][4];
    #pragma unroll
    for (int j = 0; j < NCO; j++)
        #pragma unroll
        for (int p = 0; p < 4; p++) acc[j][p] = 0.f;
    const float* ib = in + ((size_t)b * C + sl * CS) * HW;
    for (int ci = 0; ci < CS; ci++) {
        float4 v = *(const float4*)(ib + (size_t)ci * HW + x0);
        int cig = sl * CS + ci;
        #pragma unroll
        for (int j = 0; j < NCO; j++) {
            float wv = w[(size_t)(co0 + j) * C + cig];
            acc[j][0] = fmaf(v.x, wv, acc[j][0]);
            acc[j][1] = fmaf(v.y, wv, acc[j][1]);
            acc[j][2] = fmaf(v.z, wv, acc[j][2]);
            acc[j][3] = fmaf(v.w, wv, acc[j][3]);
        }
    }
    #pragma unroll
    for (int j = 0; j < NCO; j++) {
        float* op = outp + (size_t)sl * SS + ((size_t)b * C + co0 + j) * HW + x0;
        *(float4*)op = make_float4(acc[j][0], acc[j][1], acc[j][2], acc[j][3]);
    }
}

// ================= reduce partials: out = bias + sum_s part (+ res) ============
__global__ __launch_bounds__(256) void reduce_k(const float* __restrict__ part,
    const float* __restrict__ bias, const float* res, float* out,
    int HW, int Co, int NS, size_t SS)
{
    int i4 = (blockIdx.x * 256 + threadIdx.x) * 4;
    float4 a = make_float4(0.f, 0.f, 0.f, 0.f);
    for (int s = 0; s < NS; s++) {
        float4 p = *(const float4*)(part + (size_t)s * SS + i4);
        a.x += p.x; a.y += p.y; a.z += p.z; a.w += p.w;
    }
    int c = (i4 / HW) % Co;
    float bb = bias[c];
    if (res) {
        float4 r = *(const float4*)(res + i4);
        a.x += r.x; a.y += r.y; a.z += r.z; a.w += r.w;
    }
    *(float4*)(out + i4) = make_float4(a.x + bb, a.y + bb, a.z + bb, a.w + bb);
}

// ================= PAC gaussian: partial sum of d^2 (split over Cg) ============
// grid.x*256 == H*W; grid.y = B*NS
__global__ __launch_bounds__(256) void pack_d(const float* __restrict__ g,
    float* __restrict__ part, int Cg, int CS, int H, int W, int NS, size_t SS)
{
    int z = blockIdx.y;
    int b = z / NS, sl = z - b * NS;
    int p = blockIdx.x * 256 + threadIdx.x;
    int y = p / W, x = p - y * W;
    float acc[9];
    #pragma unroll
    for (int t = 0; t < 9; t++) acc[t] = 0.f;
    const float* gb = g + ((size_t)b * Cg + sl * CS) * H * W;
    for (int ci = 0; ci < CS; ci++) {
        const float* gc = gb + (size_t)ci * H * W;
        float ctr = gc[p];
        #pragma unroll
        for (int i = 0; i < 3; i++) {
            int yy = y + i - 1;
            bool yok = (yy >= 0 && yy < H);
            #pragma unroll
            for (int j = 0; j < 3; j++) {
                int xx = x + j - 1;
                float nb = (yok && xx >= 0 && xx < W) ? gc[yy * W + xx] : 0.f;
                float d = nb - ctr;
                acc[i * 3 + j] = fmaf(d, d, acc[i * 3 + j]);
            }
        }
    }
    size_t HW = (size_t)H * W;
    #pragma unroll
    for (int t = 0; t < 9; t++)
        part[(size_t)sl * SS + ((size_t)b * 9 + t) * HW + p] = acc[t];
}

// K = exp(-0.5 * sum_s part)
__global__ __launch_bounds__(256) void expcomb_k(const float* __restrict__ part,
    float* __restrict__ K, int NS, size_t SS)
{
    int i4 = (blockIdx.x * 256 + threadIdx.x) * 4;
    float4 a = make_float4(0.f, 0.f, 0.f, 0.f);
    for (int s = 0; s < NS; s++) {
        float4 p = *(const float4*)(part + (size_t)s * SS + i4);
        a.x += p.x; a.y += p.y; a.z += p.z; a.w += p.w;
    }
    *(float4*)(K + i4) = make_float4(expf(-0.5f * a.x), expf(-0.5f * a.y),
                                     expf(-0.5f * a.z), expf(-0.5f * a.w));
}

// ================= PacConvTranspose2d (k=3,s=2,p=1,op=1), wave-parity =========
template<int NCO, int NSLOT>
__device__ __forceinline__ void pacct_core(const float (*tile)[108],
    const float* __restrict__ w, int Cout, int co0, int cig0,
    const int* ti, const int* off, const float* Kv, float* acc)
{
    #pragma unroll
    for (int c = 0; c < 4; c++) {
        float sv[NSLOT];
        #pragma unroll
        for (int s = 0; s < NSLOT; s++) sv[s] = Kv[s] * tile[c][off[s]];
        const float* wr = w + ((size_t)(cig0 + c) * Cout + co0) * 9;
        #pragma unroll
        for (int j = 0; j < NCO; j++) {
            float a = acc[j];
            #pragma unroll
            for (int s = 0; s < NSLOT; s++)
                a = fmaf(sv[s], wr[j * 9 + ti[s]], a);
            acc[j] = a;
        }
    }
}

template<int NCO>
__global__ __launch_bounds__(256) void pacct_t(const float* __restrict__ xin,
    const float* __restrict__ Kk, const float* __restrict__ w,
    const float* __restrict__ bias, float* __restrict__ out,
    int Cin, int Cout, int Hi, int Wi)
{
    const int ST = 12;
    __shared__ float tile[4][9 * ST];
    int H = Hi << 1, W = Wi << 1;
    int HW = H * W, HWi = Hi * Wi;
    int tid = threadIdx.x;
    int wtiles = W >> 4;
    int sp = blockIdx.x;
    int x0 = (sp % wtiles) << 4, y0 = (sp / wtiles) << 4;
    int co0 = blockIdx.y * NCO, b = blockIdx.z;
    int wv = tid >> 6, l = tid & 63;
    int py = wv >> 1, px = wv & 1;
    int ly = l >> 3, lx = l & 7;
    int y = y0 + 2 * ly + py, x = x0 + 2 * lx + px;
    int ui0 = y0 >> 1, vi0 = x0 >> 1;
    const float* Kb = Kk + (size_t)b * 9 * HW;

    // slot tables (compile-time taps per parity branch)
    int ti[4], off[4]; float Kv[4];
    #define MKSLOT(s, I, J) { \
        const int t_ = 3 * (I) + (J); \
        int ui = (y + (I) - 1) >> 1, vi = (x + (J) - 1) >> 1; \
        ti[s] = t_; off[s] = (ui - ui0) * ST + (vi - vi0); \
        Kv[s] = Kb[(size_t)t_ * HW + y * W + x]; }
    if (py == 0 && px == 0)      { MKSLOT(0,1,1) }
    else if (py == 0)            { MKSLOT(0,1,0) MKSLOT(1,1,2) }
    else if (px == 0)            { MKSLOT(0,0,1) MKSLOT(1,2,1) }
    else                         { MKSLOT(0,0,0) MKSLOT(1,0,2) MKSLOT(2,2,0) MKSLOT(3,2,2) }
    #undef MKSLOT

    float acc[NCO];
    #pragma unroll
    for (int j = 0; j < NCO; j++) acc[j] = bias[co0 + j];
    const float* xb = xin + (size_t)b * Cin * HWi;

    for (int ci0 = 0; ci0 < Cin; ci0 += 4) {
        __syncthreads();
        for (int idx = tid; idx < 4 * 81; idx += 256) {
            int c = idx / 81, rem = idx - c * 81;
            int r = rem / 9, col = rem - r * 9;
            int ui = ui0 + r, vi = vi0 + col;
            float v = 0.f;
            if (ui < Hi && vi < Wi)
                v = xb[((size_t)(ci0 + c) * Hi + ui) * Wi + vi];
            tile[c][r * ST + col] = v;
        }
        __syncthreads();
        if (py == 0 && px == 0)
            pacct_core<NCO, 1>(tile, w, Cout, co0, ci0, ti, off, Kv, acc);
        else if (py == 0 || px == 0)
            pacct_core<NCO, 2>(tile, w, Cout, co0, ci0, ti, off, Kv, acc);
        else
            pacct_core<NCO, 4>(tile, w, Cout, co0, ci0, ti, off, Kv, acc);
    }
    #pragma unroll
    for (int j = 0; j < NCO; j++)
        out[((size_t)(b * Cout + co0 + j)) * HW + y * W + x] = acc[j];
}

// ==============================================================================
extern "C" void kernel_launch(void* const* d_in, const int* in_sizes, int n_in,
                              void* d_out, int out_size, void* d_ws, size_t ws_size,
                              hipStream_t stream)
{
    const float* x   = (const float*)d_in[0];   // (2,256,64,64)
    const float* ef2 = (const float*)d_in[1];   // (2,64,128,128)
    const float* ef1 = (const float*)d_in[2];   // (2,32,256,256)
    const float* Wd  = (const float*)d_in[3];
    const float* bd  = (const float*)d_in[4];
    const float* Wm  = (const float*)d_in[5];
    const float* bm  = (const float*)d_in[6];
    const float* Wa2 = (const float*)d_in[7];
    const float* ba2 = (const float*)d_in[8];
    const float* Wa1 = (const float*)d_in[9];
    const float* ba1 = (const float*)d_in[10];
    const float* W16 = (const float*)d_in[11];
    const float* b16 = (const float*)d_in[12];
    const float* W20 = (const float*)d_in[13];
    const float* b20 = (const float*)d_in[14];
    const float* W24 = (const float*)d_in[15];
    const float* b24 = (const float*)d_in[16];
    float* out = (float*)d_out;                 // (2,3,256,256)

    // ---- workspace regions (floats), total 16,025,600 fl = 64.1 MB ----
    float* W0 = (float*)d_ws;
    float* Z  = W0;                 // 8,388,608: P(1,1x1,adj2,pack2) / g1 / K1 / P(final)
    float* Y  = Z + 8388608;        // 4,194,304: g2 / pack1-P / x5
    float* R1 = Y + 4194304;        // 2,097,152: t0 / x3
    float* R2 = R1 + 2097152;       // 1,048,576: x1 / x2 (in-place)
    float* K2 = R2 + 1048576;       //   294,912
    float* ST = K2 + 294912;        //     1,408: stats (512+128+64)*2

    float* t0 = R1;  float* x3 = R1;
    float* x1 = R2;  float* x2 = R2;
    float* g2 = Y;   float* x5 = Y;
    float* g1 = Z;   float* K1 = Z;
    float* st0 = ST; float* st3 = ST + 1024; float* st5 = ST + 1280;

    hipMemsetAsync(ST, 0, 1408 * sizeof(float), stream);

    // 1) inorm(x) -> t0    (512 instances, HW=4096)
    istat_k<<<dim3(1024), dim3(256), 0, stream>>>(x, st0, 4096);
    iapply_k<<<dim3(2048), dim3(256), 0, stream>>>(x, st0, t0, 4096, 0);

    // 2) conv_down 256->128 @64x64: NS=8, CS=32 -> P(Z); reduce -> x1
    conv3x3_d<8><<<dim3(4, 16, 16), dim3(256), 0, stream>>>(
        t0, Wd, nullptr, Z, 256, 32, 64, 64, 128, 8, (size_t)1048576);
    reduce_k<<<dim3(1024), dim3(256), 0, stream>>>(Z, bd, nullptr, x1, 4096, 128, 8, 1048576);

    // 3) 1x1: NS=8, CS=16 -> P(Z); reduce + residual(x1) -> x2 (in-place on R2)
    conv1x1_d<8><<<dim3(4, 16, 16), dim3(256), 0, stream>>>(
        x1, Wm, Z, 128, 16, 4096, 8, (size_t)1048576);
    reduce_k<<<dim3(1024), dim3(256), 0, stream>>>(Z, bm, x1, x2, 4096, 128, 8, 1048576);

    // 4) adjust_ef_lv2 64->128 @128x128: NS=2, CS=32 -> P(Z); reduce -> g2
    conv3x3_d<8><<<dim3(16, 16, 4), dim3(256), 0, stream>>>(
        ef2, Wa2, nullptr, Z, 64, 32, 128, 128, 128, 2, (size_t)4194304);
    reduce_k<<<dim3(4096), dim3(256), 0, stream>>>(Z, ba2, nullptr, g2, 16384, 128, 2, 4194304);

    // 5) PAC kernel K2: NS=8, CS=16 -> P(Z); exp-combine -> K2
    pack_d<<<dim3(64, 16), dim3(256), 0, stream>>>(g2, Z, 128, 16, 128, 128, 8, (size_t)294912);
    expcomb_k<<<dim3(288), dim3(256), 0, stream>>>(Z, K2, 8, 294912);

    // 6) PacConvT 128->64, 64^2->128^2 -> x3 (direct, bias)
    pacct_t<8><<<dim3(64, 8, 2), dim3(256), 0, stream>>>(x2, K2, W16, b16, x3, 128, 64, 64, 64);

    // 7) double inorm+res: x3 = x3 + 2*inorm(x3)   (128 inst, HW=16384)
    istat_k<<<dim3(1024), dim3(256), 0, stream>>>(x3, st3, 16384);
    iapply_k<<<dim3(2048), dim3(256), 0, stream>>>(x3, st3, x3, 16384, 2);

    // 8) adjust_ef_lv1 32->64 @256x256 -> g1 (direct, bias)
    conv3x3_d<8><<<dim3(64, 8, 2), dim3(256), 0, stream>>>(
        ef1, Wa1, ba1, g1, 32, 32, 256, 256, 64, 1, (size_t)0);

    // 9) PAC kernel K1: NS=2, CS=32 -> P(Y); exp-combine -> K1 (Z, g1 dead)
    pack_d<<<dim3(256, 4), dim3(256), 0, stream>>>(g1, Y, 64, 32, 256, 256, 2, (size_t)1179648);
    expcomb_k<<<dim3(1152), dim3(256), 0, stream>>>(Y, K1, 2, 1179648);

    // 10) PacConvT 64->32, 128^2->256^2 -> x5 (Y; pack1-P dead)
    pacct_t<8><<<dim3(256, 4, 2), dim3(256), 0, stream>>>(x3, K1, W20, b20, x5, 64, 32, 128, 128);

    // 11) double inorm+res on x5   (64 inst, HW=65536)
    istat_k<<<dim3(2048), dim3(256), 0, stream>>>(x5, st5, 65536);
    iapply_k<<<dim3(4096), dim3(256), 0, stream>>>(x5, st5, x5, 65536, 2);

    // 12) final 32->3 @256x256: NS=4, CS=8 -> P(Z, K1 dead); reduce -> out
    conv3x3_d<3><<<dim3(64, 1, 8), dim3(256), 0, stream>>>(
        x5, W24, nullptr, Z, 32, 8, 256, 256, 3, 4, (size_t)393216);
    reduce_k<<<dim3(384), dim3(256), 0, stream>>>(Z, b24, nullptr, out, 65536, 3, 4, 393216);
}

// Round 4
// 530.963 us; speedup vs baseline: 6.4925x; 1.1922x over previous
//
#include <hip/hip_runtime.h>

#define EPS 1e-5f

// ================= InstanceNorm: stats (atomic) + apply ========================
__global__ __launch_bounds__(256) void istat_k(const float* __restrict__ in,
                                               float* st, int HW)
{
    __shared__ float sh[256], sh2[256];
    size_t base = (size_t)blockIdx.x * 2048 + threadIdx.x * 8;
    float4 a = *(const float4*)(in + base);
    float4 b = *(const float4*)(in + base + 4);
    float s  = a.x + a.y + a.z + a.w + b.x + b.y + b.z + b.w;
    float s2 = a.x*a.x + a.y*a.y + a.z*a.z + a.w*a.w
             + b.x*b.x + b.y*b.y + b.z*b.z + b.w*b.w;
    sh[threadIdx.x] = s; sh2[threadIdx.x] = s2;
    __syncthreads();
    for (int o = 128; o > 0; o >>= 1) {
        if ((int)threadIdx.x < o) {
            sh[threadIdx.x] += sh[threadIdx.x + o];
            sh2[threadIdx.x] += sh2[threadIdx.x + o];
        }
        __syncthreads();
    }
    if (threadIdx.x == 0) {
        int ch = (int)(((size_t)blockIdx.x * 2048) / (size_t)HW);
        atomicAdd(&st[2 * ch],     sh[0]);
        atomicAdd(&st[2 * ch + 1], sh2[0]);
    }
}

// mode 0: r ; mode 2: v + 2r   (in-place safe)
__global__ __launch_bounds__(256) void iapply_k(const float* in, const float* st,
                                                float* out, int HW, int mode)
{
    int i4 = (blockIdx.x * 256 + threadIdx.x) * 4;
    int ch = i4 / HW;
    float s = st[2 * ch], s2 = st[2 * ch + 1];
    float m = s / (float)HW;
    float var = s2 / (float)HW - m * m;
    float inv = rsqrtf(var + EPS);
    float4 v = *(const float4*)(in + i4);
    float4 r;
    r.x = (v.x - m) * inv; r.y = (v.y - m) * inv;
    r.z = (v.z - m) * inv; r.w = (v.w - m) * inv;
    if (mode == 2) {
        r.x = v.x + 2.f * r.x; r.y = v.y + 2.f * r.y;
        r.z = v.z + 2.f * r.z; r.w = v.w + 2.f * r.w;
    }
    *(float4*)(out + i4) = r;
}

// ================= Direct 3x3 conv (pad=1): 4 px/thread, shfl halo =============
template<int NCO>
__global__ __launch_bounds__(256) void conv3x3_d(const float* __restrict__ in,
    const float* __restrict__ w, const float* __restrict__ bias,
    float* __restrict__ outp, int Ci, int CS, int H, int W, int Co, int NS,
    size_t SS)
{
    int z = blockIdx.z;
    int b = z / NS, sl = z - b * NS;
    int WC = W >> 2;
    int idx = blockIdx.x * 256 + threadIdx.x;
    int xc = idx % WC, y = idx / WC;
    int x0 = xc << 2;
    bool lz = (x0 == 0), rz = (x0 + 4 == W);
    int co0 = blockIdx.y * NCO;
    float acc[NCO][4];
    #pragma unroll
    for (int j = 0; j < NCO; j++)
        #pragma unroll
        for (int p = 0; p < 4; p++) acc[j][p] = 0.f;

    const float* ib = in + ((size_t)b * Ci + sl * CS) * H * W;
    for (int ci = 0; ci < CS; ci++) {
        const float* ic = ib + (size_t)ci * H * W;
        float e[3][6];
        #pragma unroll
        for (int r = 0; r < 3; r++) {
            int yy = y + r - 1;
            float4 v = make_float4(0.f, 0.f, 0.f, 0.f);
            if (yy >= 0 && yy < H)
                v = *(const float4*)(ic + (size_t)yy * W + x0);
            float lf = __shfl_up(v.w, 1);
            float rt = __shfl_down(v.x, 1);
            e[r][0] = lz ? 0.f : lf;
            e[r][1] = v.x; e[r][2] = v.y; e[r][3] = v.z; e[r][4] = v.w;
            e[r][5] = rz ? 0.f : rt;
        }
        int cig = sl * CS + ci;
        #pragma unroll
        for (int j = 0; j < NCO; j++) {
            const float* wj = w + ((size_t)(co0 + j) * Ci + cig) * 9;
            #pragma unroll
            for (int r = 0; r < 3; r++) {
                float w0 = wj[3 * r], w1 = wj[3 * r + 1], w2 = wj[3 * r + 2];
                #pragma unroll
                for (int p = 0; p < 4; p++)
                    acc[j][p] = fmaf(e[r][p], w0,
                                fmaf(e[r][p + 1], w1,
                                fmaf(e[r][p + 2], w2, acc[j][p])));
            }
        }
    }
    size_t HW = (size_t)H * W;
    #pragma unroll
    for (int j = 0; j < NCO; j++) {
        float bb = bias ? bias[co0 + j] : 0.f;
        float4 o = make_float4(acc[j][0] + bb, acc[j][1] + bb,
                               acc[j][2] + bb, acc[j][3] + bb);
        float* op = outp + (size_t)sl * SS
                  + ((size_t)b * Co + co0 + j) * HW + (size_t)y * W + x0;
        *(float4*)op = o;
    }
}

// ================= Direct 1x1 conv: 4 px/thread, partial out ===================
template<int NCO>
__global__ __launch_bounds__(256) void conv1x1_d(const float* __restrict__ in,
    const float* __restrict__ w, float* __restrict__ outp,
    int C, int CS, int HW, int NS, size_t SS)
{
    int z = blockIdx.z;
    int b = z / NS, sl = z - b * NS;
    int x0 = (blockIdx.x * 256 + threadIdx.x) * 4;
    int co0 = blockIdx.y * NCO;
    float acc[NCO][4];
    #pragma unroll
    for (int j = 0; j < NCO; j++)
        #pragma unroll
        for (int p = 0; p < 4; p++) acc[j][p] = 0.f;
    const float* ib = in + ((size_t)b * C + sl * CS) * HW;
    for (int ci = 0; ci < CS; ci++) {
        float4 v = *(const float4*)(ib + (size_t)ci * HW + x0);
        int cig = sl * CS + ci;
        #pragma unroll
        for (int j = 0; j < NCO; j++) {
            float wv = w[(size_t)(co0 + j) * C + cig];
            acc[j][0] = fmaf(v.x, wv, acc[j][0]);
            acc[j][1] = fmaf(v.y, wv, acc[j][1]);
            acc[j][2] = fmaf(v.z, wv, acc[j][2]);
            acc[j][3] = fmaf(v.w, wv, acc[j][3]);
        }
    }
    #pragma unroll
    for (int j = 0; j < NCO; j++) {
        float* op = outp + (size_t)sl * SS + ((size_t)b * C + co0 + j) * HW + x0;
        *(float4*)op = make_float4(acc[j][0], acc[j][1], acc[j][2], acc[j][3]);
    }
}

// ================= reduce partials: out = bias + sum_s part (+ res) ============
__global__ __launch_bounds__(256) void reduce_k(const float* __restrict__ part,
    const float* __restrict__ bias, const float* res, float* out,
    int HW, int Co, int NS, size_t SS)
{
    int i4 = (blockIdx.x * 256 + threadIdx.x) * 4;
    float4 a = make_float4(0.f, 0.f, 0.f, 0.f);
    for (int s = 0; s < NS; s++) {
        float4 p = *(const float4*)(part + (size_t)s * SS + i4);
        a.x += p.x; a.y += p.y; a.z += p.z; a.w += p.w;
    }
    int c = (i4 / HW) % Co;
    float bb = bias[c];
    if (res) {
        float4 r = *(const float4*)(res + i4);
        a.x += r.x; a.y += r.y; a.z += r.z; a.w += r.w;
    }
    *(float4*)(out + i4) = make_float4(a.x + bb, a.y + bb, a.z + bb, a.w + bb);
}

// ================= PAC gaussian: partial sum of d^2 (split over Cg) ============
__global__ __launch_bounds__(256) void pack_d(const float* __restrict__ g,
    float* __restrict__ part, int Cg, int CS, int H, int W, int NS, size_t SS)
{
    int z = blockIdx.y;
    int b = z / NS, sl = z - b * NS;
    int p = blockIdx.x * 256 + threadIdx.x;
    int y = p / W, x = p - y * W;
    float acc[9];
    #pragma unroll
    for (int t = 0; t < 9; t++) acc[t] = 0.f;
    const float* gb = g + ((size_t)b * Cg + sl * CS) * H * W;
    for (int ci = 0; ci < CS; ci++) {
        const float* gc = gb + (size_t)ci * H * W;
        float ctr = gc[p];
        #pragma unroll
        for (int i = 0; i < 3; i++) {
            int yy = y + i - 1;
            bool yok = (yy >= 0 && yy < H);
            #pragma unroll
            for (int j = 0; j < 3; j++) {
                int xx = x + j - 1;
                float nb = (yok && xx >= 0 && xx < W) ? gc[yy * W + xx] : 0.f;
                float d = nb - ctr;
                acc[i * 3 + j] = fmaf(d, d, acc[i * 3 + j]);
            }
        }
    }
    size_t HW = (size_t)H * W;
    #pragma unroll
    for (int t = 0; t < 9; t++)
        part[(size_t)sl * SS + ((size_t)b * 9 + t) * HW + p] = acc[t];
}

__global__ __launch_bounds__(256) void expcomb_k(const float* __restrict__ part,
    float* __restrict__ K, int NS, size_t SS)
{
    int i4 = (blockIdx.x * 256 + threadIdx.x) * 4;
    float4 a = make_float4(0.f, 0.f, 0.f, 0.f);
    for (int s = 0; s < NS; s++) {
        float4 p = *(const float4*)(part + (size_t)s * SS + i4);
        a.x += p.x; a.y += p.y; a.z += p.z; a.w += p.w;
    }
    *(float4*)(K + i4) = make_float4(expf(-0.5f * a.x), expf(-0.5f * a.y),
                                     expf(-0.5f * a.z), expf(-0.5f * a.w));
}

// ================= PacConvT stage A: weight transpose wT[t][o][ci] =============
__global__ __launch_bounds__(256) void wtr_k(const float* __restrict__ w,
    float* __restrict__ wT, int Cin, int Cout)
{
    int idx = blockIdx.x * 256 + threadIdx.x;
    int n = 9 * Cout * Cin;
    if (idx >= n) return;
    int t = idx / (Cout * Cin);
    int r = idx - t * Cout * Cin;
    int o = r / Cin, ci = r - o * Cin;
    wT[idx] = w[((size_t)ci * Cout + o) * 9 + t];
}

// ================= PacConvT stage A: Gin[to][p] = sum_ci wT[to][ci]*x[ci][p] ===
// grid.x*256*4 == HWi; grid.y = TO/NCO; grid.z = batches
template<int NCO>
__global__ __launch_bounds__(256) void gemm_d(const float* __restrict__ xin,
    const float* __restrict__ wT, float* __restrict__ Gin,
    int Cin, int HWi, size_t xstride, size_t gstride)
{
    int b = blockIdx.z;
    int p0 = (blockIdx.x * 256 + threadIdx.x) * 4;
    int to0 = blockIdx.y * NCO;
    const float* xb = xin + (size_t)b * xstride;
    float acc[NCO][4];
    #pragma unroll
    for (int j = 0; j < NCO; j++)
        #pragma unroll
        for (int p = 0; p < 4; p++) acc[j][p] = 0.f;

    for (int ci = 0; ci < Cin; ci += 4) {
        float4 v[4];
        #pragma unroll
        for (int u = 0; u < 4; u++)
            v[u] = *(const float4*)(xb + (size_t)(ci + u) * HWi + p0);
        const float* vu = (const float*)v;
        #pragma unroll
        for (int j = 0; j < NCO; j++) {
            const float* wj = wT + (size_t)(to0 + j) * Cin + ci;
            float w0 = wj[0], w1 = wj[1], w2 = wj[2], w3 = wj[3];
            #pragma unroll
            for (int p = 0; p < 4; p++)
                acc[j][p] = fmaf(vu[p], w0, fmaf(vu[4 + p], w1,
                            fmaf(vu[8 + p], w2, fmaf(vu[12 + p], w3, acc[j][p]))));
        }
    }
    #pragma unroll
    for (int j = 0; j < NCO; j++)
        *(float4*)(Gin + (size_t)b * gstride + (size_t)(to0 + j) * HWi + p0) =
            make_float4(acc[j][0], acc[j][1], acc[j][2], acc[j][3]);
}

// ================= PacConvT stage B: scatter/gather ============================
// out[co,y,x] = bias[co] + sum_valid K[t,y,x]*Gin[t*Cout+co][ui,vi]
// wave-uniform row parity via split grid mapping
template<int NCO>
__global__ __launch_bounds__(256) void pacsc_k(const float* __restrict__ Gin,
    const float* __restrict__ K, const float* __restrict__ bias,
    float* __restrict__ out, int Cout, int Hi, int Wi, size_t gstride)
{
    int b = blockIdx.z;
    int H = Hi << 1, W = Wi << 1;
    int HW = H * W, HWi = Hi * Wi, WC = W >> 2;
    int idx = blockIdx.x * 256 + threadIdx.x;
    int half = (H >> 1) * WC;                 // multiple of 256 for our shapes
    int py = (idx >= half) ? 1 : 0;
    int r = idx - py * half;
    int ry = r / WC;
    int y = 2 * ry + py;
    int x0 = (r - ry * WC) << 2;
    int yi = y >> 1, xi0 = x0 >> 1;
    int co0 = blockIdx.y * NCO;
    const float* G  = Gin + (size_t)b * gstride;
    const float* Kb = K + (size_t)b * 9 * HW;
    float* ob = out + (size_t)b * Cout * HW;
    size_t krow = (size_t)y * W + x0;
    bool vok = (xi0 + 2 < Wi);

    if (py == 0) {
        float k4a = Kb[(size_t)4 * HW + krow],     k4b = Kb[(size_t)4 * HW + krow + 2];
        float k3a = Kb[(size_t)3 * HW + krow + 1], k3b = Kb[(size_t)3 * HW + krow + 3];
        float k5a = Kb[(size_t)5 * HW + krow + 1], k5b = Kb[(size_t)5 * HW + krow + 3];
        #pragma unroll
        for (int j = 0; j < NCO; j++) {
            int co = co0 + j;
            size_t rowb = (size_t)yi * Wi + xi0;
            const float* g3 = G + (size_t)(3 * Cout + co) * HWi + rowb;
            const float* g4 = G + (size_t)(4 * Cout + co) * HWi + rowb;
            const float* g5 = G + (size_t)(5 * Cout + co) * HWi + rowb;
            float bb = bias[co];
            float g5b = vok ? g5[2] : 0.f;
            float o0 = fmaf(k4a, g4[0], bb);
            float o1 = fmaf(k3a, g3[0], fmaf(k5a, g5[1], bb));
            float o2 = fmaf(k4b, g4[1], bb);
            float o3 = fmaf(k3b, g3[1], fmaf(k5b, g5b, bb));
            *(float4*)(ob + (size_t)co * HW + krow) = make_float4(o0, o1, o2, o3);
        }
    } else {
        bool yok = (yi + 1 < Hi);
        float k1a = Kb[(size_t)1 * HW + krow],     k1b = Kb[(size_t)1 * HW + krow + 2];
        float k7a = Kb[(size_t)7 * HW + krow],     k7b = Kb[(size_t)7 * HW + krow + 2];
        float k0a = Kb[(size_t)0 * HW + krow + 1], k0b = Kb[(size_t)0 * HW + krow + 3];
        float k2a = Kb[(size_t)2 * HW + krow + 1], k2b = Kb[(size_t)2 * HW + krow + 3];
        float k6a = Kb[(size_t)6 * HW + krow + 1], k6b = Kb[(size_t)6 * HW + krow + 3];
        float k8a = Kb[(size_t)8 * HW + krow + 1], k8b = Kb[(size_t)8 * HW + krow + 3];
        #pragma unroll
        for (int j = 0; j < NCO; j++) {
            int co = co0 + j;
            size_t row0 = (size_t)yi * Wi + xi0;
            size_t row1 = (size_t)(yi + 1) * Wi + xi0;
            const float* g0 = G + (size_t)(0 * Cout + co) * HWi + row0;
            const float* g1 = G + (size_t)(1 * Cout + co) * HWi + row0;
            const float* g2 = G + (size_t)(2 * Cout + co) * HWi + row0;
            const float* g6 = G + (size_t)(6 * Cout + co) * HWi + row1;
            const float* g7 = G + (size_t)(7 * Cout + co) * HWi + row1;
            const float* g8 = G + (size_t)(8 * Cout + co) * HWi + row1;
            float bb = bias[co];
            float g2b = vok ? g2[2] : 0.f;
            float g6a = yok ? g6[0] : 0.f, g6b = yok ? g6[1] : 0.f;
            float g7a = yok ? g7[0] : 0.f, g7b = yok ? g7[1] : 0.f;
            float g8a = yok ? g8[1] : 0.f;
            float g8b = (yok && vok) ? g8[2] : 0.f;
            float o0 = fmaf(k1a, g1[0], fmaf(k7a, g7a, bb));
            float o1 = fmaf(k0a, g0[0], fmaf(k2a, g2[1],
                       fmaf(k6a, g6a, fmaf(k8a, g8a, bb))));
            float o2 = fmaf(k1b, g1[1], fmaf(k7b, g7b, bb));
            float o3 = fmaf(k0b, g0[1], fmaf(k2b, g2b,
                       fmaf(k6b, g6b, fmaf(k8b, g8b, bb))));
            *(float4*)(ob + (size_t)co * HW + krow) = make_float4(o0, o1, o2, o3);
        }
    }
}

// ==============================================================================
extern "C" void kernel_launch(void* const* d_in, const int* in_sizes, int n_in,
                              void* d_out, int out_size, void* d_ws, size_t ws_size,
                              hipStream_t stream)
{
    const float* x   = (const float*)d_in[0];   // (2,256,64,64)
    const float* ef2 = (const float*)d_in[1];   // (2,64,128,128)
    const float* ef1 = (const float*)d_in[2];   // (2,32,256,256)
    const float* Wd  = (const float*)d_in[3];
    const float* bd  = (const float*)d_in[4];
    const float* Wm  = (const float*)d_in[5];
    const float* bm  = (const float*)d_in[6];
    const float* Wa2 = (const float*)d_in[7];
    const float* ba2 = (const float*)d_in[8];
    const float* Wa1 = (const float*)d_in[9];
    const float* ba1 = (const float*)d_in[10];
    const float* W16 = (const float*)d_in[11];  // (128,64,3,3)
    const float* b16 = (const float*)d_in[12];
    const float* W20 = (const float*)d_in[13];  // (64,32,3,3)
    const float* b20 = (const float*)d_in[14];
    const float* W24 = (const float*)d_in[15];
    const float* b24 = (const float*)d_in[16];
    float* out = (float*)d_out;                 // (2,3,256,256)

    // ---- workspace regions (floats), total 16,117,120 fl = 64.5 MB ----
    float* A = (float*)d_ws;        // 8,388,608 scratch: P bufs / g1 / Gin+K1 / finalP
    float* B = A + 8388608;         // 4,194,304: g2 / pack1-P / x5
    float* C = B + 4194304;         // 2,097,152: t0 / x3
    float* D = C + 2097152;         // 1,048,576: x1 / x2
    float* E = D + 1048576;         //   294,912: K2
    float* H = E + 294912;          //    93,568: wT1 + wT2 + stats

    float* t0 = C;  float* x3 = C;
    float* x1 = D;  float* x2 = D;
    float* g2 = B;  float* x5 = B;
    float* g1 = A;
    float* Gin = A;                 // A0: up to 4,718,592
    float* K1  = A + 4718592;       // A1: 1,179,648
    float* K2  = E;
    float* wT1 = H;                 // 73,728
    float* wT2 = H + 73728;         // 18,432
    float* ST  = H + 92160;         // 1,408
    float* st0 = ST; float* st3 = ST + 1024; float* st5 = ST + 1280;

    hipMemsetAsync(ST, 0, 1408 * sizeof(float), stream);
    wtr_k<<<dim3(288), dim3(256), 0, stream>>>(W16, wT1, 128, 64);
    wtr_k<<<dim3(72),  dim3(256), 0, stream>>>(W20, wT2, 64, 32);

    // 1) inorm(x) -> t0
    istat_k<<<dim3(1024), dim3(256), 0, stream>>>(x, st0, 4096);
    iapply_k<<<dim3(2048), dim3(256), 0, stream>>>(x, st0, t0, 4096, 0);

    // 2) conv_down 256->128 @64x64: NS=8, CS=32 -> P(A); reduce -> x1
    conv3x3_d<8><<<dim3(4, 16, 16), dim3(256), 0, stream>>>(
        t0, Wd, nullptr, A, 256, 32, 64, 64, 128, 8, (size_t)1048576);
    reduce_k<<<dim3(1024), dim3(256), 0, stream>>>(A, bd, nullptr, x1, 4096, 128, 8, 1048576);

    // 3) 1x1: NS=8, CS=16 -> P(A); reduce + residual -> x2
    conv1x1_d<8><<<dim3(4, 16, 16), dim3(256), 0, stream>>>(
        x1, Wm, A, 128, 16, 4096, 8, (size_t)1048576);
    reduce_k<<<dim3(1024), dim3(256), 0, stream>>>(A, bm, x1, x2, 4096, 128, 8, 1048576);

    // 4) adjust_ef_lv2 64->128 @128x128: NS=2, CS=32 -> P(A); reduce -> g2
    conv3x3_d<8><<<dim3(16, 16, 4), dim3(256), 0, stream>>>(
        ef2, Wa2, nullptr, A, 64, 32, 128, 128, 128, 2, (size_t)4194304);
    reduce_k<<<dim3(4096), dim3(256), 0, stream>>>(A, ba2, nullptr, g2, 16384, 128, 2, 4194304);

    // 5) PAC kernel K2: NS=8, CS=16 -> P(A); exp-combine -> K2
    pack_d<<<dim3(64, 16), dim3(256), 0, stream>>>(g2, A, 128, 16, 128, 128, 8, (size_t)294912);
    expcomb_k<<<dim3(288), dim3(256), 0, stream>>>(A, K2, 8, 294912);

    // 6) PacConvT #1 128->64, 64^2->128^2: GEMM (TO=576) + scatter -> x3
    gemm_d<8><<<dim3(4, 72, 2), dim3(256), 0, stream>>>(
        x2, wT1, Gin, 128, 4096, (size_t)524288, (size_t)2359296);
    pacsc_k<2><<<dim3(16, 32, 2), dim3(256), 0, stream>>>(
        Gin, K2, b16, x3, 64, 64, 64, (size_t)2359296);

    // 7) double inorm+res: x3 = x3 + 2*inorm(x3)
    istat_k<<<dim3(1024), dim3(256), 0, stream>>>(x3, st3, 16384);
    iapply_k<<<dim3(2048), dim3(256), 0, stream>>>(x3, st3, x3, 16384, 2);

    // 8) adjust_ef_lv1 32->64 @256x256 -> g1(A) (direct, bias)
    conv3x3_d<8><<<dim3(64, 8, 2), dim3(256), 0, stream>>>(
        ef1, Wa1, ba1, g1, 32, 32, 256, 256, 64, 1, (size_t)0);

    // 9) PAC kernel K1: NS=2, CS=32 -> P(B); exp-combine -> K1(A1)
    pack_d<<<dim3(256, 4), dim3(256), 0, stream>>>(g1, B, 64, 32, 256, 256, 2, (size_t)1179648);
    expcomb_k<<<dim3(1152), dim3(256), 0, stream>>>(B, K1, 2, 1179648);

    // 10) PacConvT #2 64->32, 128^2->256^2, per-batch (Gin = 288*16384 fits A0)
    for (int b = 0; b < 2; b++) {
        gemm_d<8><<<dim3(16, 36, 1), dim3(256), 0, stream>>>(
            x3 + (size_t)b * 64 * 16384, wT2, Gin, 64, 16384, (size_t)0, (size_t)0);
        pacsc_k<2><<<dim3(64, 16, 1), dim3(256), 0, stream>>>(
            Gin, K1 + (size_t)b * 9 * 65536, b20, x5 + (size_t)b * 32 * 65536,
            32, 128, 128, (size_t)0);
    }

    // 11) double inorm+res on x5
    istat_k<<<dim3(2048), dim3(256), 0, stream>>>(x5, st5, 65536);
    iapply_k<<<dim3(4096), dim3(256), 0, stream>>>(x5, st5, x5, 65536, 2);

    // 12) final 32->3 @256x256: NS=4, CS=8 -> P(A); reduce -> out
    conv3x3_d<3><<<dim3(64, 1, 8), dim3(256), 0, stream>>>(
        x5, W24, nullptr, A, 32, 8, 256, 256, 3, 4, (size_t)393216);
    reduce_k<<<dim3(384), dim3(256), 0, stream>>>(A, b24, nullptr, out, 65536, 3, 4, 393216);
}

// Round 5
// 469.975 us; speedup vs baseline: 7.3351x; 1.1298x over previous
//
#include <hip/hip_runtime.h>

#define EPS 1e-5f

typedef short sh8 __attribute__((ext_vector_type(8)));    // 8 x bf16 (4 VGPR)
typedef float f32x4 __attribute__((ext_vector_type(4)));  // MFMA acc frag

__device__ __forceinline__ ushort f2b(float f) {
    unsigned u = __float_as_uint(f);
    u += 0x7fffu + ((u >> 16) & 1u);          // RNE
    return (ushort)(u >> 16);
}

// ================= InstanceNorm: stats (atomic) + apply ========================
__global__ __launch_bounds__(256) void istat_k(const float* __restrict__ in,
                                               float* st, int HW)
{
    __shared__ float sh[256], sh2[256];
    size_t base = (size_t)blockIdx.x * 2048 + threadIdx.x * 8;
    float4 a = *(const float4*)(in + base);
    float4 b = *(const float4*)(in + base + 4);
    float s  = a.x + a.y + a.z + a.w + b.x + b.y + b.z + b.w;
    float s2 = a.x*a.x + a.y*a.y + a.z*a.z + a.w*a.w
             + b.x*b.x + b.y*b.y + b.z*b.z + b.w*b.w;
    sh[threadIdx.x] = s; sh2[threadIdx.x] = s2;
    __syncthreads();
    for (int o = 128; o > 0; o >>= 1) {
        if ((int)threadIdx.x < o) {
            sh[threadIdx.x] += sh[threadIdx.x + o];
            sh2[threadIdx.x] += sh2[threadIdx.x + o];
        }
        __syncthreads();
    }
    if (threadIdx.x == 0) {
        int ch = (int)(((size_t)blockIdx.x * 2048) / (size_t)HW);
        atomicAdd(&st[2 * ch],     sh[0]);
        atomicAdd(&st[2 * ch + 1], sh2[0]);
    }
}

__global__ __launch_bounds__(256) void iapply_k(const float* in, const float* st,
                                                float* out, int HW, int mode)
{
    int i4 = (blockIdx.x * 256 + threadIdx.x) * 4;
    int ch = i4 / HW;
    float s = st[2 * ch], s2 = st[2 * ch + 1];
    float m = s / (float)HW;
    float var = s2 / (float)HW - m * m;
    float inv = rsqrtf(var + EPS);
    float4 v = *(const float4*)(in + i4);
    float4 r;
    r.x = (v.x - m) * inv; r.y = (v.y - m) * inv;
    r.z = (v.z - m) * inv; r.w = (v.w - m) * inv;
    if (mode == 2) {
        r.x = v.x + 2.f * r.x; r.y = v.y + 2.f * r.y;
        r.z = v.z + 2.f * r.z; r.w = v.w + 2.f * r.w;
    }
    *(float4*)(out + i4) = r;
}

// ================= stage: NCHW f32 -> (padded) NHWC bf16 =======================
__global__ __launch_bounds__(256) void pad_k(const float* __restrict__ in,
    ushort* __restrict__ ob, int C, int H, int W, int pad, int n4)
{
    int idx = blockIdx.x * 256 + threadIdx.x;
    if (idx >= n4) return;
    int b = blockIdx.y;
    int cpp = C >> 2;
    int pp = idx / cpp, c0 = (idx - pp * cpp) * 4;
    int Wp = W + 2 * pad, Hp = H + 2 * pad;
    int yp = pp / Wp, xp = pp - yp * Wp;
    int y = yp - pad, x = xp - pad;
    ushort4 o;
    if (y >= 0 && y < H && x >= 0 && x < W) {
        const float* ib = in + ((size_t)b * C) * H * W + (size_t)y * W + x;
        size_t HW = (size_t)H * W;
        o.x = f2b(ib[(size_t)(c0    ) * HW]);
        o.y = f2b(ib[(size_t)(c0 + 1) * HW]);
        o.z = f2b(ib[(size_t)(c0 + 2) * HW]);
        o.w = f2b(ib[(size_t)(c0 + 3) * HW]);
    } else { o.x = o.y = o.z = o.w = 0; }
    *(ushort4*)(ob + ((size_t)b * Hp * Wp + pp) * C + c0) = o;
}

// ================= weight transforms to bf16 ===================================
// conv OIHW w[co][ci][t] -> wb[co][t][ci]
__global__ __launch_bounds__(256) void wtb_k(const float* __restrict__ w,
    ushort* __restrict__ wb, int Ci, int n)
{
    int idx = blockIdx.x * 256 + threadIdx.x;
    if (idx >= n) return;
    int co = idx / (9 * Ci);
    int r = idx - co * 9 * Ci;
    int t = r / Ci, ci = r - t * Ci;
    wb[idx] = f2b(w[((size_t)co * Ci + ci) * 9 + t]);
}
// pacct convT (Ci,Cout,3,3) -> wb[to=t*Cout+o][ci]
__global__ __launch_bounds__(256) void wtb2_k(const float* __restrict__ w,
    ushort* __restrict__ wb, int Ci, int Cout, int n)
{
    int idx = blockIdx.x * 256 + threadIdx.x;
    if (idx >= n) return;
    int to = idx / Ci, ci = idx - to * Ci;
    int t = to / Cout, o = to - t * Cout;
    wb[idx] = f2b(w[((size_t)ci * Cout + o) * 9 + t]);
}

// ================= unified MFMA GEMM: out[n][p] = sum_{t,ci} in[p+off_t][ci]*w[n][t][ci]
// block 256 = 4 waves, each wave: 64 px x 16 n; taps=9 (padded in) or 1
template<int CI>
__global__ __launch_bounds__(256) void mgemm_k(
    const ushort* __restrict__ inb, const ushort* __restrict__ wb,
    const float* __restrict__ bias, float* __restrict__ outp,
    int wshift, int Wp, int taps, int NS, int CSL, size_t SS,
    size_t in_bstride, size_t out_bstride, int HW)
{
    int z = blockIdx.z;
    int b = z / NS, sl = z - b * NS;
    int cilo = sl * CSL, cihi = cilo + CSL;
    int tid = threadIdx.x;
    int wv = tid >> 6, l = tid & 63;
    int lane16 = l & 15, quad = l >> 4;
    int klane = quad * 8;
    int W = 1 << wshift;
    int pblk = blockIdx.x * 256 + wv * 64;
    int base[4];
    #pragma unroll
    for (int mt = 0; mt < 4; mt++) {
        int pm = pblk + mt * 16 + lane16;
        if (taps == 9) {
            int y = pm >> wshift, x = pm & (W - 1);
            base[mt] = (y + 1) * Wp + (x + 1);
        } else base[mt] = pm;
    }
    int n = blockIdx.y * 16 + lane16;
    const ushort* inbb = inb + (size_t)b * in_bstride;
    size_t wbase = (size_t)n * taps * CI + klane;
    f32x4 vz = {0.f, 0.f, 0.f, 0.f};
    f32x4 acc[4] = {vz, vz, vz, vz};

    for (int t = 0; t < taps; t++) {
        int dof = (taps == 9) ? ((t / 3 - 1) * Wp + (t % 3 - 1)) : 0;
        const ushort* wrow = wb + wbase + (size_t)t * CI;
        for (int ci = cilo; ci < cihi; ci += 32) {
            sh8 bf = *(const sh8*)(wrow + ci);
            #pragma unroll
            for (int mt = 0; mt < 4; mt++) {
                sh8 af = *(const sh8*)(inbb + (size_t)(base[mt] + dof) * CI + ci + klane);
                acc[mt] = __builtin_amdgcn_mfma_f32_16x16x32_bf16(af, bf, acc[mt], 0, 0, 0);
            }
        }
    }
    float bb = bias ? bias[n] : 0.f;
    float* ob = outp + (size_t)sl * SS + (size_t)b * out_bstride + (size_t)n * HW;
    #pragma unroll
    for (int mt = 0; mt < 4; mt++) {
        int p0 = pblk + mt * 16 + quad * 4;
        *(float4*)(ob + p0) = make_float4(acc[mt][0] + bb, acc[mt][1] + bb,
                                          acc[mt][2] + bb, acc[mt][3] + bb);
    }
}

// ================= Direct 3x3 conv fp32 (kept for final 32->3) =================
template<int NCO>
__global__ __launch_bounds__(256) void conv3x3_d(const float* __restrict__ in,
    const float* __restrict__ w, const float* __restrict__ bias,
    float* __restrict__ outp, int Ci, int CS, int H, int W, int Co, int NS,
    size_t SS)
{
    int z = blockIdx.z;
    int b = z / NS, sl = z - b * NS;
    int WC = W >> 2;
    int idx = blockIdx.x * 256 + threadIdx.x;
    int xc = idx % WC, y = idx / WC;
    int x0 = xc << 2;
    bool lz = (x0 == 0), rz = (x0 + 4 == W);
    int co0 = blockIdx.y * NCO;
    float acc[NCO][4];
    #pragma unroll
    for (int j = 0; j < NCO; j++)
        #pragma unroll
        for (int p = 0; p < 4; p++) acc[j][p] = 0.f;

    const float* ib = in + ((size_t)b * Ci + sl * CS) * H * W;
    for (int ci = 0; ci < CS; ci++) {
        const float* ic = ib + (size_t)ci * H * W;
        float e[3][6];
        #pragma unroll
        for (int r = 0; r < 3; r++) {
            int yy = y + r - 1;
            float4 v = make_float4(0.f, 0.f, 0.f, 0.f);
            if (yy >= 0 && yy < H)
                v = *(const float4*)(ic + (size_t)yy * W + x0);
            float lf = __shfl_up(v.w, 1);
            float rt = __shfl_down(v.x, 1);
            e[r][0] = lz ? 0.f : lf;
            e[r][1] = v.x; e[r][2] = v.y; e[r][3] = v.z; e[r][4] = v.w;
            e[r][5] = rz ? 0.f : rt;
        }
        int cig = sl * CS + ci;
        #pragma unroll
        for (int j = 0; j < NCO; j++) {
            const float* wj = w + ((size_t)(co0 + j) * Ci + cig) * 9;
            #pragma unroll
            for (int r = 0; r < 3; r++) {
                float w0 = wj[3 * r], w1 = wj[3 * r + 1], w2 = wj[3 * r + 2];
                #pragma unroll
                for (int p = 0; p < 4; p++)
                    acc[j][p] = fmaf(e[r][p], w0,
                                fmaf(e[r][p + 1], w1,
                                fmaf(e[r][p + 2], w2, acc[j][p])));
            }
        }
    }
    size_t HW = (size_t)H * W;
    #pragma unroll
    for (int j = 0; j < NCO; j++) {
        float bb = bias ? bias[co0 + j] : 0.f;
        float4 o = make_float4(acc[j][0] + bb, acc[j][1] + bb,
                               acc[j][2] + bb, acc[j][3] + bb);
        float* op = outp + (size_t)sl * SS
                  + ((size_t)b * Co + co0 + j) * HW + (size_t)y * W + x0;
        *(float4*)op = o;
    }
}

// ================= Direct 1x1 conv fp32 (kept) =================================
template<int NCO>
__global__ __launch_bounds__(256) void conv1x1_d(const float* __restrict__ in,
    const float* __restrict__ w, float* __restrict__ outp,
    int C, int CS, int HW, int NS, size_t SS)
{
    int z = blockIdx.z;
    int b = z / NS, sl = z - b * NS;
    int x0 = (blockIdx.x * 256 + threadIdx.x) * 4;
    int co0 = blockIdx.y * NCO;
    float acc[NCO][4];
    #pragma unroll
    for (int j = 0; j < NCO; j++)
        #pragma unroll
        for (int p = 0; p < 4; p++) acc[j][p] = 0.f;
    const float* ib = in + ((size_t)b * C + sl * CS) * HW;
    for (int ci = 0; ci < CS; ci++) {
        float4 v = *(const float4*)(ib + (size_t)ci * HW + x0);
        int cig = sl * CS + ci;
        #pragma unroll
        for (int j = 0; j < NCO; j++) {
            float wv = w[(size_t)(co0 + j) * C + cig];
            acc[j][0] = fmaf(v.x, wv, acc[j][0]);
            acc[j][1] = fmaf(v.y, wv, acc[j][1]);
            acc[j][2] = fmaf(v.z, wv, acc[j][2]);
            acc[j][3] = fmaf(v.w, wv, acc[j][3]);
        }
    }
    #pragma unroll
    for (int j = 0; j < NCO; j++) {
        float* op = outp + (size_t)sl * SS + ((size_t)b * C + co0 + j) * HW + x0;
        *(float4*)op = make_float4(acc[j][0], acc[j][1], acc[j][2], acc[j][3]);
    }
}

// ================= reduce partials =============================================
__global__ __launch_bounds__(256) void reduce_k(const float* __restrict__ part,
    const float* __restrict__ bias, const float* res, float* out,
    int HW, int Co, int NS, size_t SS)
{
    int i4 = (blockIdx.x * 256 + threadIdx.x) * 4;
    float4 a = make_float4(0.f, 0.f, 0.f, 0.f);
    for (int s = 0; s < NS; s++) {
        float4 p = *(const float4*)(part + (size_t)s * SS + i4);
        a.x += p.x; a.y += p.y; a.z += p.z; a.w += p.w;
    }
    int c = (i4 / HW) % Co;
    float bb = bias[c];
    if (res) {
        float4 r = *(const float4*)(res + i4);
        a.x += r.x; a.y += r.y; a.z += r.z; a.w += r.w;
    }
    *(float4*)(out + i4) = make_float4(a.x + bb, a.y + bb, a.z + bb, a.w + bb);
}

// ================= PAC gaussian ================================================
__global__ __launch_bounds__(256) void pack_d(const float* __restrict__ g,
    float* __restrict__ part, int Cg, int CS, int H, int W, int NS, size_t SS)
{
    int z = blockIdx.y;
    int b = z / NS, sl = z - b * NS;
    int p = blockIdx.x * 256 + threadIdx.x;
    int y = p / W, x = p - y * W;
    float acc[9];
    #pragma unroll
    for (int t = 0; t < 9; t++) acc[t] = 0.f;
    const float* gb = g + ((size_t)b * Cg + sl * CS) * H * W;
    for (int ci = 0; ci < CS; ci++) {
        const float* gc = gb + (size_t)ci * H * W;
        float ctr = gc[p];
        #pragma unroll
        for (int i = 0; i < 3; i++) {
            int yy = y + i - 1;
            bool yok = (yy >= 0 && yy < H);
            #pragma unroll
            for (int j = 0; j < 3; j++) {
                int xx = x + j - 1;
                float nb = (yok && xx >= 0 && xx < W) ? gc[yy * W + xx] : 0.f;
                float d = nb - ctr;
                acc[i * 3 + j] = fmaf(d, d, acc[i * 3 + j]);
            }
        }
    }
    size_t HW = (size_t)H * W;
    #pragma unroll
    for (int t = 0; t < 9; t++)
        part[(size_t)sl * SS + ((size_t)b * 9 + t) * HW + p] = acc[t];
}

__global__ __launch_bounds__(256) void expcomb_k(const float* __restrict__ part,
    float* __restrict__ K, int NS, size_t SS)
{
    int i4 = (blockIdx.x * 256 + threadIdx.x) * 4;
    float4 a = make_float4(0.f, 0.f, 0.f, 0.f);
    for (int s = 0; s < NS; s++) {
        float4 p = *(const float4*)(part + (size_t)s * SS + i4);
        a.x += p.x; a.y += p.y; a.z += p.z; a.w += p.w;
    }
    *(float4*)(K + i4) = make_float4(expf(-0.5f * a.x), expf(-0.5f * a.y),
                                     expf(-0.5f * a.z), expf(-0.5f * a.w));
}

// ================= PacConvT stage B: scatter/gather ============================
template<int NCO>
__global__ __launch_bounds__(256) void pacsc_k(const float* __restrict__ Gin,
    const float* __restrict__ K, const float* __restrict__ bias,
    float* __restrict__ out, int Cout, int Hi, int Wi, size_t gstride)
{
    int b = blockIdx.z;
    int H = Hi << 1, W = Wi << 1;
    int HW = H * W, HWi = Hi * Wi, WC = W >> 2;
    int idx = blockIdx.x * 256 + threadIdx.x;
    int half = (H >> 1) * WC;
    int py = (idx >= half) ? 1 : 0;
    int r = idx - py * half;
    int ry = r / WC;
    int y = 2 * ry + py;
    int x0 = (r - ry * WC) << 2;
    int yi = y >> 1, xi0 = x0 >> 1;
    int co0 = blockIdx.y * NCO;
    const float* G  = Gin + (size_t)b * gstride;
    const float* Kb = K + (size_t)b * 9 * HW;
    float* ob = out + (size_t)b * Cout * HW;
    size_t krow = (size_t)y * W + x0;
    bool vok = (xi0 + 2 < Wi);

    if (py == 0) {
        float k4a = Kb[(size_t)4 * HW + krow],     k4b = Kb[(size_t)4 * HW + krow + 2];
        float k3a = Kb[(size_t)3 * HW + krow + 1], k3b = Kb[(size_t)3 * HW + krow + 3];
        float k5a = Kb[(size_t)5 * HW + krow + 1], k5b = Kb[(size_t)5 * HW + krow + 3];
        #pragma unroll
        for (int j = 0; j < NCO; j++) {
            int co = co0 + j;
            size_t rowb = (size_t)yi * Wi + xi0;
            const float* g3 = G + (size_t)(3 * Cout + co) * HWi + rowb;
            const float* g4 = G + (size_t)(4 * Cout + co) * HWi + rowb;
            const float* g5 = G + (size_t)(5 * Cout + co) * HWi + rowb;
            float bb = bias[co];
            float g5b = vok ? g5[2] : 0.f;
            float o0 = fmaf(k4a, g4[0], bb);
            float o1 = fmaf(k3a, g3[0], fmaf(k5a, g5[1], bb));
            float o2 = fmaf(k4b, g4[1], bb);
            float o3 = fmaf(k3b, g3[1], fmaf(k5b, g5b, bb));
            *(float4*)(ob + (size_t)co * HW + krow) = make_float4(o0, o1, o2, o3);
        }
    } else {
        bool yok = (yi + 1 < Hi);
        float k1a = Kb[(size_t)1 * HW + krow],     k1b = Kb[(size_t)1 * HW + krow + 2];
        float k7a = Kb[(size_t)7 * HW + krow],     k7b = Kb[(size_t)7 * HW + krow + 2];
        float k0a = Kb[(size_t)0 * HW + krow + 1], k0b = Kb[(size_t)0 * HW + krow + 3];
        float k2a = Kb[(size_t)2 * HW + krow + 1], k2b = Kb[(size_t)2 * HW + krow + 3];
        float k6a = Kb[(size_t)6 * HW + krow + 1], k6b = Kb[(size_t)6 * HW + krow + 3];
        float k8a = Kb[(size_t)8 * HW + krow + 1], k8b = Kb[(size_t)8 * HW + krow + 3];
        #pragma unroll
        for (int j = 0; j < NCO; j++) {
            int co = co0 + j;
            size_t row0 = (size_t)yi * Wi + xi0;
            size_t row1 = (size_t)(yi + 1) * Wi + xi0;
            const float* g0 = G + (size_t)(0 * Cout + co) * HWi + row0;
            const float* g1 = G + (size_t)(1 * Cout + co) * HWi + row0;
            const float* g2 = G + (size_t)(2 * Cout + co) * HWi + row0;
            const float* g6 = G + (size_t)(6 * Cout + co) * HWi + row1;
            const float* g7 = G + (size_t)(7 * Cout + co) * HWi + row1;
            const float* g8 = G + (size_t)(8 * Cout + co) * HWi + row1;
            float bb = bias[co];
            float g2b = vok ? g2[2] : 0.f;
            float g6a = yok ? g6[0] : 0.f, g6b = yok ? g6[1] : 0.f;
            float g7a = yok ? g7[0] : 0.f, g7b = yok ? g7[1] : 0.f;
            float g8a = yok ? g8[1] : 0.f;
            float g8b = (yok && vok) ? g8[2] : 0.f;
            float o0 = fmaf(k1a, g1[0], fmaf(k7a, g7a, bb));
            float o1 = fmaf(k0a, g0[0], fmaf(k2a, g2[1],
                       fmaf(k6a, g6a, fmaf(k8a, g8a, bb))));
            float o2 = fmaf(k1b, g1[1], fmaf(k7b, g7b, bb));
            float o3 = fmaf(k0b, g0[1], fmaf(k2b, g2b,
                       fmaf(k6b, g6b, fmaf(k8b, g8b, bb))));
            *(float4*)(ob + (size_t)co * HW + krow) = make_float4(o0, o1, o2, o3);
        }
    }
}

// ==============================================================================
extern "C" void kernel_launch(void* const* d_in, const int* in_sizes, int n_in,
                              void* d_out, int out_size, void* d_ws, size_t ws_size,
                              hipStream_t stream)
{
    const float* x   = (const float*)d_in[0];   // (2,256,64,64)
    const float* ef2 = (const float*)d_in[1];   // (2,64,128,128)
    const float* ef1 = (const float*)d_in[2];   // (2,32,256,256)
    const float* Wd  = (const float*)d_in[3];
    const float* bd  = (const float*)d_in[4];
    const float* Wm  = (const float*)d_in[5];
    const float* bm  = (const float*)d_in[6];
    const float* Wa2 = (const float*)d_in[7];
    const float* ba2 = (const float*)d_in[8];
    const float* Wa1 = (const float*)d_in[9];
    const float* ba1 = (const float*)d_in[10];
    const float* W16 = (const float*)d_in[11];  // (128,64,3,3)
    const float* b16 = (const float*)d_in[12];
    const float* W20 = (const float*)d_in[13];  // (64,32,3,3)
    const float* b20 = (const float*)d_in[14];
    const float* W24 = (const float*)d_in[15];
    const float* b24 = (const float*)d_in[16];
    float* out = (float*)d_out;                 // (2,3,256,256)

    // ---- workspace regions (floats), same 64.5 MB footprint as R4 ----
    float* A = (float*)d_ws;        // 8,388,608
    float* B = A + 8388608;         // 4,194,304
    float* C = B + 4194304;         // 2,097,152: t0 / x3
    float* D = C + 2097152;         // 1,048,576: x1 / x2
    float* E = D + 1048576;         //   294,912: K2
    float* Hh = E + 294912;         //    93,568: wT1b/wT2b bf16 + stats

    float* t0 = C;  float* x3 = C;
    float* x1 = D;  float* x2 = D;
    float* g2 = B;  float* x5 = B;
    float* g1 = A;
    float* Gin = A;                       // A0: up to 4,718,592
    float* K1  = A + 4718592;             // 1,179,648
    float* K2  = E;

    // bf16 staging buffers (ushort), placed in dead windows
    ushort* padDb  = (ushort*)A;                  // 2,230,272 us (step 2)
    ushort* wbD    = (ushort*)(A + 1115136);      //   294,912 us
    float*  Pd     = A + 1262592;                 // 2x1,048,576 (conv_down partials)
    ushort* padA2b = (ushort*)A;                  // 2,163,200 us (step 4)
    ushort* wbA2b  = (ushort*)(A + 1081600);      //    73,728 us
    ushort* padA1b = (ushort*)B;                  // 4,260,096 us (step 8)
    ushort* wbA1b  = (ushort*)(B + 2130048);      //    18,432 us
    ushort* x2b    = (ushort*)(A + 4718592);      // 1,048,576 us (step 6)
    ushort* x3b    = (ushort*)(A + 5898240);      // 2,097,152 us (step 10)
    ushort* wT1b   = (ushort*)Hh;                 //    73,728 us
    ushort* wT2b   = (ushort*)(Hh + 36864);       //    18,432 us
    float*  ST     = Hh + 46080;                  //     1,408
    float* st0 = ST; float* st3 = ST + 1024; float* st5 = ST + 1280;

    hipMemsetAsync(ST, 0, 1408 * sizeof(float), stream);
    wtb2_k<<<dim3(288), dim3(256), 0, stream>>>(W16, wT1b, 128, 64, 73728);
    wtb2_k<<<dim3(72),  dim3(256), 0, stream>>>(W20, wT2b, 64, 32, 18432);

    // 1) inorm(x) -> t0
    istat_k<<<dim3(1024), dim3(256), 0, stream>>>(x, st0, 4096);
    iapply_k<<<dim3(2048), dim3(256), 0, stream>>>(x, st0, t0, 4096, 0);

    // 2) conv_down 256->128 @64x64 via MFMA (K-split 2) -> P; reduce -> x1
    pad_k<<<dim3(1089, 2), dim3(256), 0, stream>>>(t0, padDb, 256, 64, 64, 1, 278784);
    wtb_k<<<dim3(1152), dim3(256), 0, stream>>>(Wd, wbD, 256, 294912);
    mgemm_k<256><<<dim3(16, 8, 4), dim3(256), 0, stream>>>(
        padDb, wbD, nullptr, Pd, 6, 66, 9, 2, 128, (size_t)1048576,
        (size_t)1115136, (size_t)524288, 4096);
    reduce_k<<<dim3(1024), dim3(256), 0, stream>>>(Pd, bd, nullptr, x1, 4096, 128, 2, 1048576);

    // 3) 1x1 fp32: NS=8 -> P(A); reduce + residual -> x2
    conv1x1_d<8><<<dim3(4, 16, 16), dim3(256), 0, stream>>>(
        x1, Wm, A, 128, 16, 4096, 8, (size_t)1048576);
    reduce_k<<<dim3(1024), dim3(256), 0, stream>>>(A, bm, x1, x2, 4096, 128, 8, 1048576);

    // 4) adjust_ef_lv2 64->128 @128x128 via MFMA -> g2
    pad_k<<<dim3(1057, 2), dim3(256), 0, stream>>>(ef2, padA2b, 64, 128, 128, 1, 270400);
    wtb_k<<<dim3(288), dim3(256), 0, stream>>>(Wa2, wbA2b, 64, 73728);
    mgemm_k<64><<<dim3(64, 8, 2), dim3(256), 0, stream>>>(
        padA2b, wbA2b, ba2, g2, 7, 130, 9, 1, 64, (size_t)0,
        (size_t)1081600, (size_t)2097152, 16384);

    // 5) PAC kernel K2: NS=8 -> P(A); exp-combine -> K2
    pack_d<<<dim3(64, 16), dim3(256), 0, stream>>>(g2, A, 128, 16, 128, 128, 8, (size_t)294912);
    expcomb_k<<<dim3(288), dim3(256), 0, stream>>>(A, K2, 8, 294912);

    // 6) PacConvT #1: stage x2 -> bf16; MFMA GEMM (N=576) -> Gin; scatter -> x3
    pad_k<<<dim3(512, 2), dim3(256), 0, stream>>>(x2, x2b, 128, 64, 64, 0, 131072);
    mgemm_k<128><<<dim3(16, 36, 2), dim3(256), 0, stream>>>(
        x2b, wT1b, nullptr, Gin, 6, 0, 1, 1, 128, (size_t)0,
        (size_t)524288, (size_t)2359296, 4096);
    pacsc_k<2><<<dim3(16, 32, 2), dim3(256), 0, stream>>>(
        Gin, K2, b16, x3, 64, 64, 64, (size_t)2359296);

    // 7) double inorm+res: x3 = x3 + 2*inorm(x3)
    istat_k<<<dim3(1024), dim3(256), 0, stream>>>(x3, st3, 16384);
    iapply_k<<<dim3(2048), dim3(256), 0, stream>>>(x3, st3, x3, 16384, 2);

    // 8) adjust_ef_lv1 32->64 @256x256 via MFMA -> g1(A)
    pad_k<<<dim3(2081, 2), dim3(256), 0, stream>>>(ef1, padA1b, 32, 256, 256, 1, 532512);
    wtb_k<<<dim3(72), dim3(256), 0, stream>>>(Wa1, wbA1b, 32, 18432);
    mgemm_k<32><<<dim3(256, 4, 2), dim3(256), 0, stream>>>(
        padA1b, wbA1b, ba1, g1, 8, 258, 9, 1, 32, (size_t)0,
        (size_t)2130048, (size_t)4194304, 65536);

    // 9) PAC kernel K1: NS=2 -> P(B); exp-combine -> K1(A-tail)
    pack_d<<<dim3(256, 4), dim3(256), 0, stream>>>(g1, B, 64, 32, 256, 256, 2, (size_t)1179648);
    expcomb_k<<<dim3(1152), dim3(256), 0, stream>>>(B, K1, 2, 1179648);

    // 10) PacConvT #2: stage x3 -> bf16 (both b); per-batch MFMA GEMM + scatter
    pad_k<<<dim3(1024, 2), dim3(256), 0, stream>>>(x3, x3b, 64, 128, 128, 0, 262144);
    for (int b = 0; b < 2; b++) {
        mgemm_k<64><<<dim3(64, 18, 1), dim3(256), 0, stream>>>(
            x3b + (size_t)b * 1048576, wT2b, nullptr, Gin, 7, 0, 1, 1, 64,
            (size_t)0, (size_t)0, (size_t)0, 16384);
        pacsc_k<2><<<dim3(64, 16, 1), dim3(256), 0, stream>>>(
            Gin, K1 + (size_t)b * 9 * 65536, b20, x5 + (size_t)b * 32 * 65536,
            32, 128, 128, (size_t)0);
    }

    // 11) double inorm+res on x5
    istat_k<<<dim3(2048), dim3(256), 0, stream>>>(x5, st5, 65536);
    iapply_k<<<dim3(4096), dim3(256), 0, stream>>>(x5, st5, x5, 65536, 2);

    // 12) final 32->3 @256x256 fp32: NS=4 -> P(A); reduce -> out
    conv3x3_d<3><<<dim3(64, 1, 8), dim3(256), 0, stream>>>(
        x5, W24, nullptr, A, 32, 8, 256, 256, 3, 4, (size_t)393216);
    reduce_k<<<dim3(384), dim3(256), 0, stream>>>(A, b24, nullptr, out, 65536, 3, 4, 393216);
}

// Round 6
// 448.768 us; speedup vs baseline: 7.6817x; 1.0473x over previous
//
#include <hip/hip_runtime.h>

#define EPS 1e-5f

typedef short sh8 __attribute__((ext_vector_type(8)));    // 8 x bf16 (4 VGPR)
typedef float f32x4 __attribute__((ext_vector_type(4)));  // MFMA acc frag

__device__ __forceinline__ ushort f2b(float f) {
    unsigned u = __float_as_uint(f);
    u += 0x7fffu + ((u >> 16) & 1u);          // RNE
    return (ushort)(u >> 16);
}

// ================= InstanceNorm: stats (atomic) + apply ========================
__global__ __launch_bounds__(256) void istat_k(const float* __restrict__ in,
                                               float* st, int HW)
{
    __shared__ float sh[256], sh2[256];
    size_t base = (size_t)blockIdx.x * 2048 + threadIdx.x * 8;
    float4 a = *(const float4*)(in + base);
    float4 b = *(const float4*)(in + base + 4);
    float s  = a.x + a.y + a.z + a.w + b.x + b.y + b.z + b.w;
    float s2 = a.x*a.x + a.y*a.y + a.z*a.z + a.w*a.w
             + b.x*b.x + b.y*b.y + b.z*b.z + b.w*b.w;
    sh[threadIdx.x] = s; sh2[threadIdx.x] = s2;
    __syncthreads();
    for (int o = 128; o > 0; o >>= 1) {
        if ((int)threadIdx.x < o) {
            sh[threadIdx.x] += sh[threadIdx.x + o];
            sh2[threadIdx.x] += sh2[threadIdx.x + o];
        }
        __syncthreads();
    }
    if (threadIdx.x == 0) {
        int ch = (int)(((size_t)blockIdx.x * 2048) / (size_t)HW);
        atomicAdd(&st[2 * ch],     sh[0]);
        atomicAdd(&st[2 * ch + 1], sh2[0]);
    }
}

__global__ __launch_bounds__(256) void iapply_k(const float* in, const float* st,
                                                float* out, int HW, int mode)
{
    int i4 = (blockIdx.x * 256 + threadIdx.x) * 4;
    int ch = i4 / HW;
    float s = st[2 * ch], s2 = st[2 * ch + 1];
    float m = s / (float)HW;
    float var = s2 / (float)HW - m * m;
    float inv = rsqrtf(var + EPS);
    float4 v = *(const float4*)(in + i4);
    float4 r;
    r.x = (v.x - m) * inv; r.y = (v.y - m) * inv;
    r.z = (v.z - m) * inv; r.w = (v.w - m) * inv;
    if (mode == 2) {
        r.x = v.x + 2.f * r.x; r.y = v.y + 2.f * r.y;
        r.z = v.z + 2.f * r.z; r.w = v.w + 2.f * r.w;
    }
    *(float4*)(out + i4) = r;
}

// ================= stage: NCHW f32 -> (padded) NHWC bf16 =======================
__global__ __launch_bounds__(256) void pad_k(const float* __restrict__ in,
    ushort* __restrict__ ob, int C, int H, int W, int pad, int n4)
{
    int idx = blockIdx.x * 256 + threadIdx.x;
    if (idx >= n4) return;
    int b = blockIdx.y;
    int cpp = C >> 2;
    int pp = idx / cpp, c0 = (idx - pp * cpp) * 4;
    int Wp = W + 2 * pad, Hp = H + 2 * pad;
    int yp = pp / Wp, xp = pp - yp * Wp;
    int y = yp - pad, x = xp - pad;
    ushort4 o;
    if (y >= 0 && y < H && x >= 0 && x < W) {
        const float* ib = in + ((size_t)b * C) * H * W + (size_t)y * W + x;
        size_t HW = (size_t)H * W;
        o.x = f2b(ib[(size_t)(c0    ) * HW]);
        o.y = f2b(ib[(size_t)(c0 + 1) * HW]);
        o.z = f2b(ib[(size_t)(c0 + 2) * HW]);
        o.w = f2b(ib[(size_t)(c0 + 3) * HW]);
    } else { o.x = o.y = o.z = o.w = 0; }
    *(ushort4*)(ob + ((size_t)b * Hp * Wp + pp) * C + c0) = o;
}

// ================= weight transforms to bf16 ===================================
__global__ __launch_bounds__(256) void wtb_k(const float* __restrict__ w,
    ushort* __restrict__ wb, int Ci, int n)
{
    int idx = blockIdx.x * 256 + threadIdx.x;
    if (idx >= n) return;
    int co = idx / (9 * Ci);
    int r = idx - co * 9 * Ci;
    int t = r / Ci, ci = r - t * Ci;
    wb[idx] = f2b(w[((size_t)co * Ci + ci) * 9 + t]);
}
__global__ __launch_bounds__(256) void wtb2_k(const float* __restrict__ w,
    ushort* __restrict__ wb, int Ci, int Cout, int n)
{
    int idx = blockIdx.x * 256 + threadIdx.x;
    if (idx >= n) return;
    int to = idx / Ci, ci = idx - to * Ci;
    int t = to / Cout, o = to - t * Cout;
    wb[idx] = f2b(w[((size_t)ci * Cout + o) * 9 + t]);
}

// ================= MFMA GEMM v2: reg-tiled 2x2, software-pipelined =============
// wave: 32 px x 32 n; NWX=2: block 64px x 64n (2x2 waves); NWX=1: 128px x 32n
template<int CI, int TAPS, int NWX>
__global__ __launch_bounds__(256) void mg2_k(
    const ushort* __restrict__ inb, const ushort* __restrict__ wb,
    const float* __restrict__ bias, float* __restrict__ outp,
    int wshift, int Wp, int NS, int CSL, int nchs, size_t SS,
    size_t in_bstride, size_t out_bstride, int HW)
{
    int z = blockIdx.z;
    int b = z / NS, sl = z - b * NS;
    int cilo = sl * CSL;
    int tid = threadIdx.x;
    int wv = tid >> 6, l = tid & 63;
    int lane16 = l & 15, quad = l >> 4;
    int klane = quad * 8;
    int wy, wx;
    if (NWX == 2) { wy = wv & 1; wx = wv >> 1; }
    else          { wy = wv;     wx = 0; }
    const int PXB = (NWX == 2) ? 64 : 128;
    int pb = blockIdx.x * PXB + wy * 32;
    int nb = blockIdx.y * (NWX * 32) + wx * 32;

    int base[2];
    #pragma unroll
    for (int i = 0; i < 2; i++) {
        int pm = pb + i * 16 + lane16;
        if (TAPS == 9) {
            int W = 1 << wshift;
            int y = pm >> wshift, xx = pm & (W - 1);
            base[i] = (y + 1) * Wp + (xx + 1);
        } else base[i] = pm;
    }
    int nn[2];
    nn[0] = nb + lane16; nn[1] = nb + 16 + lane16;

    const ushort* inbb = inb + (size_t)b * in_bstride + cilo + klane;
    const ushort* wbb  = wb + cilo + klane;

    f32x4 vz = {0.f, 0.f, 0.f, 0.f};
    f32x4 acc[2][2] = {{vz, vz}, {vz, vz}};
    sh8 a[2], bf[2], an[2], bn[2];
    int totk = TAPS << nchs;

    #define LDK(kk, av, bv) { \
        int t_ = (kk) >> nchs, c_ = (kk) - (t_ << nchs); \
        int dof_ = 0; \
        if (TAPS == 9) { \
            int dy_ = (t_ * 43) >> 7; \
            int dx_ = t_ - dy_ * 3; \
            dof_ = (dy_ - 1) * Wp + (dx_ - 1); \
        } \
        int coff_ = c_ << 5; \
        av[0] = *(const sh8*)(inbb + (size_t)(base[0] + dof_) * CI + coff_); \
        av[1] = *(const sh8*)(inbb + (size_t)(base[1] + dof_) * CI + coff_); \
        bv[0] = *(const sh8*)(wbb + ((size_t)nn[0] * TAPS + t_) * CI + coff_); \
        bv[1] = *(const sh8*)(wbb + ((size_t)nn[1] * TAPS + t_) * CI + coff_); \
    }

    LDK(0, a, bf)
    for (int kk = 0; kk < totk; kk++) {
        if (kk + 1 < totk) LDK(kk + 1, an, bn)
        acc[0][0] = __builtin_amdgcn_mfma_f32_16x16x32_bf16(a[0], bf[0], acc[0][0], 0, 0, 0);
        acc[0][1] = __builtin_amdgcn_mfma_f32_16x16x32_bf16(a[0], bf[1], acc[0][1], 0, 0, 0);
        acc[1][0] = __builtin_amdgcn_mfma_f32_16x16x32_bf16(a[1], bf[0], acc[1][0], 0, 0, 0);
        acc[1][1] = __builtin_amdgcn_mfma_f32_16x16x32_bf16(a[1], bf[1], acc[1][1], 0, 0, 0);
        a[0] = an[0]; a[1] = an[1]; bf[0] = bn[0]; bf[1] = bn[1];
    }
    #undef LDK

    float* ob = outp + (size_t)sl * SS + (size_t)b * out_bstride;
    #pragma unroll
    for (int j = 0; j < 2; j++) {
        float bb = bias ? bias[nn[j]] : 0.f;
        #pragma unroll
        for (int i = 0; i < 2; i++) {
            int p0 = pb + i * 16 + quad * 4;
            *(float4*)(ob + (size_t)nn[j] * HW + p0) =
                make_float4(acc[i][j][0] + bb, acc[i][j][1] + bb,
                            acc[i][j][2] + bb, acc[i][j][3] + bb);
        }
    }
}

// ================= Direct 3x3 conv fp32 (final 32->3) ==========================
template<int NCO>
__global__ __launch_bounds__(256) void conv3x3_d(const float* __restrict__ in,
    const float* __restrict__ w, const float* __restrict__ bias,
    float* __restrict__ outp, int Ci, int CS, int H, int W, int Co, int NS,
    size_t SS)
{
    int z = blockIdx.z;
    int b = z / NS, sl = z - b * NS;
    int WC = W >> 2;
    int idx = blockIdx.x * 256 + threadIdx.x;
    int xc = idx % WC, y = idx / WC;
    int x0 = xc << 2;
    bool lz = (x0 == 0), rz = (x0 + 4 == W);
    int co0 = blockIdx.y * NCO;
    float acc[NCO][4];
    #pragma unroll
    for (int j = 0; j < NCO; j++)
        #pragma unroll
        for (int p = 0; p < 4; p++) acc[j][p] = 0.f;

    const float* ib = in + ((size_t)b * Ci + sl * CS) * H * W;
    for (int ci = 0; ci < CS; ci++) {
        const float* ic = ib + (size_t)ci * H * W;
        float e[3][6];
        #pragma unroll
        for (int r = 0; r < 3; r++) {
            int yy = y + r - 1;
            float4 v = make_float4(0.f, 0.f, 0.f, 0.f);
            if (yy >= 0 && yy < H)
                v = *(const float4*)(ic + (size_t)yy * W + x0);
            float lf = __shfl_up(v.w, 1);
            float rt = __shfl_down(v.x, 1);
            e[r][0] = lz ? 0.f : lf;
            e[r][1] = v.x; e[r][2] = v.y; e[r][3] = v.z; e[r][4] = v.w;
            e[r][5] = rz ? 0.f : rt;
        }
        int cig = sl * CS + ci;
        #pragma unroll
        for (int j = 0; j < NCO; j++) {
            const float* wj = w + ((size_t)(co0 + j) * Ci + cig) * 9;
            #pragma unroll
            for (int r = 0; r < 3; r++) {
                float w0 = wj[3 * r], w1 = wj[3 * r + 1], w2 = wj[3 * r + 2];
                #pragma unroll
                for (int p = 0; p < 4; p++)
                    acc[j][p] = fmaf(e[r][p], w0,
                                fmaf(e[r][p + 1], w1,
                                fmaf(e[r][p + 2], w2, acc[j][p])));
            }
        }
    }
    size_t HW = (size_t)H * W;
    #pragma unroll
    for (int j = 0; j < NCO; j++) {
        float bb = bias ? bias[co0 + j] : 0.f;
        float4 o = make_float4(acc[j][0] + bb, acc[j][1] + bb,
                               acc[j][2] + bb, acc[j][3] + bb);
        float* op = outp + (size_t)sl * SS
                  + ((size_t)b * Co + co0 + j) * HW + (size_t)y * W + x0;
        *(float4*)op = o;
    }
}

// ================= Direct 1x1 conv fp32 ========================================
template<int NCO>
__global__ __launch_bounds__(256) void conv1x1_d(const float* __restrict__ in,
    const float* __restrict__ w, float* __restrict__ outp,
    int C, int CS, int HW, int NS, size_t SS)
{
    int z = blockIdx.z;
    int b = z / NS, sl = z - b * NS;
    int x0 = (blockIdx.x * 256 + threadIdx.x) * 4;
    int co0 = blockIdx.y * NCO;
    float acc[NCO][4];
    #pragma unroll
    for (int j = 0; j < NCO; j++)
        #pragma unroll
        for (int p = 0; p < 4; p++) acc[j][p] = 0.f;
    const float* ib = in + ((size_t)b * C + sl * CS) * HW;
    for (int ci = 0; ci < CS; ci++) {
        float4 v = *(const float4*)(ib + (size_t)ci * HW + x0);
        int cig = sl * CS + ci;
        #pragma unroll
        for (int j = 0; j < NCO; j++) {
            float wv = w[(size_t)(co0 + j) * C + cig];
            acc[j][0] = fmaf(v.x, wv, acc[j][0]);
            acc[j][1] = fmaf(v.y, wv, acc[j][1]);
            acc[j][2] = fmaf(v.z, wv, acc[j][2]);
            acc[j][3] = fmaf(v.w, wv, acc[j][3]);
        }
    }
    #pragma unroll
    for (int j = 0; j < NCO; j++) {
        float* op = outp + (size_t)sl * SS + ((size_t)b * C + co0 + j) * HW + x0;
        *(float4*)op = make_float4(acc[j][0], acc[j][1], acc[j][2], acc[j][3]);
    }
}

// ================= reduce partials =============================================
__global__ __launch_bounds__(256) void reduce_k(const float* __restrict__ part,
    const float* __restrict__ bias, const float* res, float* out,
    int HW, int Co, int NS, size_t SS)
{
    int i4 = (blockIdx.x * 256 + threadIdx.x) * 4;
    float4 a = make_float4(0.f, 0.f, 0.f, 0.f);
    for (int s = 0; s < NS; s++) {
        float4 p = *(const float4*)(part + (size_t)s * SS + i4);
        a.x += p.x; a.y += p.y; a.z += p.z; a.w += p.w;
    }
    int c = (i4 / HW) % Co;
    float bb = bias[c];
    if (res) {
        float4 r = *(const float4*)(res + i4);
        a.x += r.x; a.y += r.y; a.z += r.z; a.w += r.w;
    }
    *(float4*)(out + i4) = make_float4(a.x + bb, a.y + bb, a.z + bb, a.w + bb);
}

// ================= PAC gaussian ================================================
__global__ __launch_bounds__(256) void pack_d(const float* __restrict__ g,
    float* __restrict__ part, int Cg, int CS, int H, int W, int NS, size_t SS)
{
    int z = blockIdx.y;
    int b = z / NS, sl = z - b * NS;
    int p = blockIdx.x * 256 + threadIdx.x;
    int y = p / W, x = p - y * W;
    float acc[9];
    #pragma unroll
    for (int t = 0; t < 9; t++) acc[t] = 0.f;
    const float* gb = g + ((size_t)b * Cg + sl * CS) * H * W;
    for (int ci = 0; ci < CS; ci++) {
        const float* gc = gb + (size_t)ci * H * W;
        float ctr = gc[p];
        #pragma unroll
        for (int i = 0; i < 3; i++) {
            int yy = y + i - 1;
            bool yok = (yy >= 0 && yy < H);
            #pragma unroll
            for (int j = 0; j < 3; j++) {
                int xx = x + j - 1;
                float nb = (yok && xx >= 0 && xx < W) ? gc[yy * W + xx] : 0.f;
                float d = nb - ctr;
                acc[i * 3 + j] = fmaf(d, d, acc[i * 3 + j]);
            }
        }
    }
    size_t HW = (size_t)H * W;
    #pragma unroll
    for (int t = 0; t < 9; t++)
        part[(size_t)sl * SS + ((size_t)b * 9 + t) * HW + p] = acc[t];
}

__global__ __launch_bounds__(256) void expcomb_k(const float* __restrict__ part,
    float* __restrict__ K, int NS, size_t SS)
{
    int i4 = (blockIdx.x * 256 + threadIdx.x) * 4;
    float4 a = make_float4(0.f, 0.f, 0.f, 0.f);
    for (int s = 0; s < NS; s++) {
        float4 p = *(const float4*)(part + (size_t)s * SS + i4);
        a.x += p.x; a.y += p.y; a.z += p.z; a.w += p.w;
    }
    *(float4*)(K + i4) = make_float4(expf(-0.5f * a.x), expf(-0.5f * a.y),
                                     expf(-0.5f * a.z), expf(-0.5f * a.w));
}

// ================= PacConvT stage B: scatter/gather ============================
template<int NCO>
__global__ __launch_bounds__(256) void pacsc_k(const float* __restrict__ Gin,
    const float* __restrict__ K, const float* __restrict__ bias,
    float* __restrict__ out, int Cout, int Hi, int Wi, size_t gstride)
{
    int b = blockIdx.z;
    int H = Hi << 1, W = Wi << 1;
    int HW = H * W, HWi = Hi * Wi, WC = W >> 2;
    int idx = blockIdx.x * 256 + threadIdx.x;
    int half = (H >> 1) * WC;
    int py = (idx >= half) ? 1 : 0;
    int r = idx - py * half;
    int ry = r / WC;
    int y = 2 * ry + py;
    int x0 = (r - ry * WC) << 2;
    int yi = y >> 1, xi0 = x0 >> 1;
    int co0 = blockIdx.y * NCO;
    const float* G  = Gin + (size_t)b * gstride;
    const float* Kb = K + (size_t)b * 9 * HW;
    float* ob = out + (size_t)b * Cout * HW;
    size_t krow = (size_t)y * W + x0;
    bool vok = (xi0 + 2 < Wi);

    if (py == 0) {
        float k4a = Kb[(size_t)4 * HW + krow],     k4b = Kb[(size_t)4 * HW + krow + 2];
        float k3a = Kb[(size_t)3 * HW + krow + 1], k3b = Kb[(size_t)3 * HW + krow + 3];
        float k5a = Kb[(size_t)5 * HW + krow + 1], k5b = Kb[(size_t)5 * HW + krow + 3];
        #pragma unroll
        for (int j = 0; j < NCO; j++) {
            int co = co0 + j;
            size_t rowb = (size_t)yi * Wi + xi0;
            const float* g3 = G + (size_t)(3 * Cout + co) * HWi + rowb;
            const float* g4 = G + (size_t)(4 * Cout + co) * HWi + rowb;
            const float* g5 = G + (size_t)(5 * Cout + co) * HWi + rowb;
            float bb = bias[co];
            float g5b = vok ? g5[2] : 0.f;
            float o0 = fmaf(k4a, g4[0], bb);
            float o1 = fmaf(k3a, g3[0], fmaf(k5a, g5[1], bb));
            float o2 = fmaf(k4b, g4[1], bb);
            float o3 = fmaf(k3b, g3[1], fmaf(k5b, g5b, bb));
            *(float4*)(ob + (size_t)co * HW + krow) = make_float4(o0, o1, o2, o3);
        }
    } else {
        bool yok = (yi + 1 < Hi);
        float k1a = Kb[(size_t)1 * HW + krow],     k1b = Kb[(size_t)1 * HW + krow + 2];
        float k7a = Kb[(size_t)7 * HW + krow],     k7b = Kb[(size_t)7 * HW + krow + 2];
        float k0a = Kb[(size_t)0 * HW + krow + 1], k0b = Kb[(size_t)0 * HW + krow + 3];
        float k2a = Kb[(size_t)2 * HW + krow + 1], k2b = Kb[(size_t)2 * HW + krow + 3];
        float k6a = Kb[(size_t)6 * HW + krow + 1], k6b = Kb[(size_t)6 * HW + krow + 3];
        float k8a = Kb[(size_t)8 * HW + krow + 1], k8b = Kb[(size_t)8 * HW + krow + 3];
        #pragma unroll
        for (int j = 0; j < NCO; j++) {
            int co = co0 + j;
            size_t row0 = (size_t)yi * Wi + xi0;
            size_t row1 = (size_t)(yi + 1) * Wi + xi0;
            const float* g0 = G + (size_t)(0 * Cout + co) * HWi + row0;
            const float* g1 = G + (size_t)(1 * Cout + co) * HWi + row0;
            const float* g2 = G + (size_t)(2 * Cout + co) * HWi + row0;
            const float* g6 = G + (size_t)(6 * Cout + co) * HWi + row1;
            const float* g7 = G + (size_t)(7 * Cout + co) * HWi + row1;
            const float* g8 = G + (size_t)(8 * Cout + co) * HWi + row1;
            float bb = bias[co];
            float g2b = vok ? g2[2] : 0.f;
            float g6a = yok ? g6[0] : 0.f, g6b = yok ? g6[1] : 0.f;
            float g7a = yok ? g7[0] : 0.f, g7b = yok ? g7[1] : 0.f;
            float g8a = yok ? g8[1] : 0.f;
            float g8b = (yok && vok) ? g8[2] : 0.f;
            float o0 = fmaf(k1a, g1[0], fmaf(k7a, g7a, bb));
            float o1 = fmaf(k0a, g0[0], fmaf(k2a, g2[1],
                       fmaf(k6a, g6a, fmaf(k8a, g8a, bb))));
            float o2 = fmaf(k1b, g1[1], fmaf(k7b, g7b, bb));
            float o3 = fmaf(k0b, g0[1], fmaf(k2b, g2b,
                       fmaf(k6b, g6b, fmaf(k8b, g8b, bb))));
            *(float4*)(ob + (size_t)co * HW + krow) = make_float4(o0, o1, o2, o3);
        }
    }
}

// ==============================================================================
extern "C" void kernel_launch(void* const* d_in, const int* in_sizes, int n_in,
                              void* d_out, int out_size, void* d_ws, size_t ws_size,
                              hipStream_t stream)
{
    const float* x   = (const float*)d_in[0];   // (2,256,64,64)
    const float* ef2 = (const float*)d_in[1];   // (2,64,128,128)
    const float* ef1 = (const float*)d_in[2];   // (2,32,256,256)
    const float* Wd  = (const float*)d_in[3];
    const float* bd  = (const float*)d_in[4];
    const float* Wm  = (const float*)d_in[5];
    const float* bm  = (const float*)d_in[6];
    const float* Wa2 = (const float*)d_in[7];
    const float* ba2 = (const float*)d_in[8];
    const float* Wa1 = (const float*)d_in[9];
    const float* ba1 = (const float*)d_in[10];
    const float* W16 = (const float*)d_in[11];  // (128,64,3,3)
    const float* b16 = (const float*)d_in[12];
    const float* W20 = (const float*)d_in[13];  // (64,32,3,3)
    const float* b20 = (const float*)d_in[14];
    const float* W24 = (const float*)d_in[15];
    const float* b24 = (const float*)d_in[16];
    float* out = (float*)d_out;                 // (2,3,256,256)

    // ---- workspace regions (floats), same 64.5 MB footprint ----
    float* A = (float*)d_ws;        // 8,388,608
    float* B = A + 8388608;         // 4,194,304
    float* C = B + 4194304;         // 2,097,152: t0 / x3
    float* D = C + 2097152;         // 1,048,576: x1 / x2
    float* E = D + 1048576;         //   294,912: K2
    float* Hh = E + 294912;         //    93,568: wT1b/wT2b bf16 + stats

    float* t0 = C;  float* x3 = C;
    float* x1 = D;  float* x2 = D;
    float* g2 = B;  float* x5 = B;
    float* g1 = A;
    float* Gin = A;                       // A0: up to 4,718,592
    float* K1  = A + 4718592;             // 1,179,648
    float* K2  = E;

    // bf16 staging buffers (ushort), placed in dead windows
    ushort* padDb  = (ushort*)A;                  // 2,230,272 us (step 2)
    ushort* wbD    = (ushort*)(A + 1115136);      //   294,912 us
    float*  Pd     = A + 1262592;                 // 4x1,048,576 fl (conv_down partials)
    ushort* padA2b = (ushort*)A;                  // 2,163,200 us (step 4)
    ushort* wbA2b  = (ushort*)(A + 1081600);      //    73,728 us
    ushort* padA1b = (ushort*)B;                  // 4,260,096 us (step 8)
    ushort* wbA1b  = (ushort*)(B + 2130048);      //    18,432 us
    ushort* x2b    = (ushort*)(A + 4718592);      // 1,048,576 us (step 6)
    ushort* x3b    = (ushort*)(A + 5898240);      // 2,097,152 us (step 10)
    ushort* wT1b   = (ushort*)Hh;                 //    73,728 us
    ushort* wT2b   = (ushort*)(Hh + 36864);       //    18,432 us
    float*  ST     = Hh + 46080;                  //     1,408
    float* st0 = ST; float* st3 = ST + 1024; float* st5 = ST + 1280;

    hipMemsetAsync(ST, 0, 1408 * sizeof(float), stream);
    wtb2_k<<<dim3(288), dim3(256), 0, stream>>>(W16, wT1b, 128, 64, 73728);
    wtb2_k<<<dim3(72),  dim3(256), 0, stream>>>(W20, wT2b, 64, 32, 18432);

    // 1) inorm(x) -> t0
    istat_k<<<dim3(1024), dim3(256), 0, stream>>>(x, st0, 4096);
    iapply_k<<<dim3(2048), dim3(256), 0, stream>>>(x, st0, t0, 4096, 0);

    // 2) conv_down 256->128 @64x64 via MFMA (K-split 4) -> Pd; reduce -> x1
    pad_k<<<dim3(1089, 2), dim3(256), 0, stream>>>(t0, padDb, 256, 64, 64, 1, 278784);
    wtb_k<<<dim3(1152), dim3(256), 0, stream>>>(Wd, wbD, 256, 294912);
    mg2_k<256, 9, 2><<<dim3(64, 2, 8), dim3(256), 0, stream>>>(
        padDb, wbD, nullptr, Pd, 6, 66, 4, 64, 1, (size_t)1048576,
        (size_t)1115136, (size_t)524288, 4096);
    reduce_k<<<dim3(1024), dim3(256), 0, stream>>>(Pd, bd, nullptr, x1, 4096, 128, 4, 1048576);

    // 3) 1x1 fp32: NS=8 -> P(A); reduce + residual -> x2
    conv1x1_d<8><<<dim3(4, 16, 16), dim3(256), 0, stream>>>(
        x1, Wm, A, 128, 16, 4096, 8, (size_t)1048576);
    reduce_k<<<dim3(1024), dim3(256), 0, stream>>>(A, bm, x1, x2, 4096, 128, 8, 1048576);

    // 4) adjust_ef_lv2 64->128 @128x128 via MFMA -> g2
    pad_k<<<dim3(1057, 2), dim3(256), 0, stream>>>(ef2, padA2b, 64, 128, 128, 1, 270400);
    wtb_k<<<dim3(288), dim3(256), 0, stream>>>(Wa2, wbA2b, 64, 73728);
    mg2_k<64, 9, 2><<<dim3(256, 2, 2), dim3(256), 0, stream>>>(
        padA2b, wbA2b, ba2, g2, 7, 130, 1, 64, 1, (size_t)0,
        (size_t)1081600, (size_t)2097152, 16384);

    // 5) PAC kernel K2: NS=8 -> P(A); exp-combine -> K2
    pack_d<<<dim3(64, 16), dim3(256), 0, stream>>>(g2, A, 128, 16, 128, 128, 8, (size_t)294912);
    expcomb_k<<<dim3(288), dim3(256), 0, stream>>>(A, K2, 8, 294912);

    // 6) PacConvT #1: stage x2 -> bf16; MFMA GEMM (N=576) -> Gin; scatter -> x3
    pad_k<<<dim3(512, 2), dim3(256), 0, stream>>>(x2, x2b, 128, 64, 64, 0, 131072);
    mg2_k<128, 1, 2><<<dim3(64, 9, 2), dim3(256), 0, stream>>>(
        x2b, wT1b, nullptr, Gin, 6, 0, 1, 128, 2, (size_t)0,
        (size_t)524288, (size_t)2359296, 4096);
    pacsc_k<2><<<dim3(16, 32, 2), dim3(256), 0, stream>>>(
        Gin, K2, b16, x3, 64, 64, 64, (size_t)2359296);

    // 7) double inorm+res: x3 = x3 + 2*inorm(x3)
    istat_k<<<dim3(1024), dim3(256), 0, stream>>>(x3, st3, 16384);
    iapply_k<<<dim3(2048), dim3(256), 0, stream>>>(x3, st3, x3, 16384, 2);

    // 8) adjust_ef_lv1 32->64 @256x256 via MFMA -> g1(A)
    pad_k<<<dim3(2081, 2), dim3(256), 0, stream>>>(ef1, padA1b, 32, 256, 256, 1, 532512);
    wtb_k<<<dim3(72), dim3(256), 0, stream>>>(Wa1, wbA1b, 32, 18432);
    mg2_k<32, 9, 2><<<dim3(1024, 1, 2), dim3(256), 0, stream>>>(
        padA1b, wbA1b, ba1, g1, 8, 258, 1, 32, 0, (size_t)0,
        (size_t)2130048, (size_t)4194304, 65536);

    // 9) PAC kernel K1: NS=2 -> P(B); exp-combine -> K1(A-tail)
    pack_d<<<dim3(256, 4), dim3(256), 0, stream>>>(g1, B, 64, 32, 256, 256, 2, (size_t)1179648);
    expcomb_k<<<dim3(1152), dim3(256), 0, stream>>>(B, K1, 2, 1179648);

    // 10) PacConvT #2: stage x3 -> bf16 (both b); per-batch MFMA GEMM + scatter
    pad_k<<<dim3(1024, 2), dim3(256), 0, stream>>>(x3, x3b, 64, 128, 128, 0, 262144);
    for (int b = 0; b < 2; b++) {
        mg2_k<64, 1, 1><<<dim3(128, 9, 1), dim3(256), 0, stream>>>(
            x3b + (size_t)b * 1048576, wT2b, nullptr, Gin, 7, 0, 1, 64, 1,
            (size_t)0, (size_t)0, (size_t)0, 16384);
        pacsc_k<2><<<dim3(64, 16, 1), dim3(256), 0, stream>>>(
            Gin, K1 + (size_t)b * 9 * 65536, b20, x5 + (size_t)b * 32 * 65536,
            32, 128, 128, (size_t)0);
    }

    // 11) double inorm+res on x5
    istat_k<<<dim3(2048), dim3(256), 0, stream>>>(x5, st5, 65536);
    iapply_k<<<dim3(4096), dim3(256), 0, stream>>>(x5, st5, x5, 65536, 2);

    // 12) final 32->3 @256x256 fp32: NS=4 -> P(A); reduce -> out
    conv3x3_d<3><<<dim3(64, 1, 8), dim3(256), 0, stream>>>(
        x5, W24, nullptr, A, 32, 8, 256, 256, 3, 4, (size_t)393216);
    reduce_k<<<dim3(384), dim3(256), 0, stream>>>(A, b24, nullptr, out, 65536, 3, 4, 393216);
}